// Round 1
// baseline (1447.980 us; speedup 1.0000x reference)
//
#include <hip/hip_runtime.h>
#include <hip/hip_bf16.h>
#include <math.h>

// B=65536 samples. Fused pipeline:
//  hero MLP (140->32->32->16) x10 heroes
//  counter MLP (32->16->16->8) over 50 (i,j) pairs, factorized layer-1 (u_i + v_j)
//  maxpool(2) + max over 25 pairs -> g1/g2 [4]
//  team MLP (84->64->64->16) x2 halves
//  final MLP (32->16->16->2) + softmax
// One workgroup = 256 threads handles SPB=8 samples; everything after the
// x-read lives in LDS.

#define SPB 8
#define NROWS (SPB * 10)   // 80 hero rows per workgroup
#define THREADS 256

__global__ __launch_bounds__(THREADS, 4) void fused_model_kernel(
    const float* __restrict__ x,
    const float* __restrict__ h_w1, const float* __restrict__ h_b1,
    const float* __restrict__ h_w2, const float* __restrict__ h_b2,
    const float* __restrict__ h_w3, const float* __restrict__ h_b3,
    const float* __restrict__ c_w1, const float* __restrict__ c_b1,
    const float* __restrict__ c_w2, const float* __restrict__ c_b2,
    const float* __restrict__ c_w3, const float* __restrict__ c_b3,
    const float* __restrict__ t_w1, const float* __restrict__ t_b1,
    const float* __restrict__ t_w2, const float* __restrict__ t_b2,
    const float* __restrict__ t_w3, const float* __restrict__ t_b3,
    const float* __restrict__ f_w1, const float* __restrict__ f_b1,
    const float* __restrict__ f_w2, const float* __restrict__ f_b2,
    const float* __restrict__ f_w3, const float* __restrict__ f_b3,
    float* __restrict__ out)
{
    // LDS buffers (floats). Row stride 36 keeps float4 alignment (144B) and
    // staggers banks (36 mod 32 = 4).
    __shared__ float sA[NROWS * 36];   // h1; later u(0..15)/v(16..31); later team staging
    __shared__ float sB[NROWS * 36];   // h2; later pooled counter outputs [8][50][4]
    __shared__ float sHO[NROWS * 20];  // hero outputs, row stride 20
    __shared__ float sG[SPB * 8];      // g1|g2 per sample
    __shared__ float sT[SPB * 32];     // team outputs (concat halves)
    __shared__ float sF1[SPB * 16];
    __shared__ float sF2[SPB * 16];

    const int tid = threadIdx.x;
    const int wg = blockIdx.x;
    const int s0 = wg * SPB;                     // first sample
    const float* xg = x + (size_t)s0 * 1400;     // 10*140 per sample

    // ---------------- Phase A1: hero layer 1 (140 -> 32) ----------------
    {
        const int slot = tid >> 3;        // 0..31  (row)
        const int sub  = tid & 7;         // 0..7
        const int o0 = sub << 2;          // 4 outputs per thread
        for (int r = slot; r < NROWS; r += 32) {
            const float* xr = xg + r * 140;
            float a0 = 0.f, a1 = 0.f, a2 = 0.f, a3 = 0.f;
            for (int k = 0; k < 140; k += 4) {
                const float4 xv = *(const float4*)(xr + k);
                const float4 w0 = *(const float4*)(h_w1 + (k + 0) * 32 + o0);
                const float4 w1v = *(const float4*)(h_w1 + (k + 1) * 32 + o0);
                const float4 w2v = *(const float4*)(h_w1 + (k + 2) * 32 + o0);
                const float4 w3v = *(const float4*)(h_w1 + (k + 3) * 32 + o0);
                a0 += xv.x * w0.x + xv.y * w1v.x + xv.z * w2v.x + xv.w * w3v.x;
                a1 += xv.x * w0.y + xv.y * w1v.y + xv.z * w2v.y + xv.w * w3v.y;
                a2 += xv.x * w0.z + xv.y * w1v.z + xv.z * w2v.z + xv.w * w3v.z;
                a3 += xv.x * w0.w + xv.y * w1v.w + xv.z * w2v.w + xv.w * w3v.w;
            }
            const float4 bb = *(const float4*)(h_b1 + o0);
            float4 res;
            res.x = fmaxf(a0 + bb.x, 0.f);
            res.y = fmaxf(a1 + bb.y, 0.f);
            res.z = fmaxf(a2 + bb.z, 0.f);
            res.w = fmaxf(a3 + bb.w, 0.f);
            *(float4*)(&sA[r * 36 + o0]) = res;
        }
    }
    __syncthreads();

    // ---------------- Phase A2: hero layer 2 (32 -> 32) ----------------
    {
        const int slot = tid >> 3;
        const int sub  = tid & 7;
        const int o0 = sub << 2;
        for (int r = slot; r < NROWS; r += 32) {
            float a0 = 0.f, a1 = 0.f, a2 = 0.f, a3 = 0.f;
            #pragma unroll
            for (int k = 0; k < 32; k += 4) {
                const float4 hv = *(const float4*)(&sA[r * 36 + k]);
                const float4 w0 = *(const float4*)(h_w2 + (k + 0) * 32 + o0);
                const float4 w1v = *(const float4*)(h_w2 + (k + 1) * 32 + o0);
                const float4 w2v = *(const float4*)(h_w2 + (k + 2) * 32 + o0);
                const float4 w3v = *(const float4*)(h_w2 + (k + 3) * 32 + o0);
                a0 += hv.x * w0.x + hv.y * w1v.x + hv.z * w2v.x + hv.w * w3v.x;
                a1 += hv.x * w0.y + hv.y * w1v.y + hv.z * w2v.y + hv.w * w3v.y;
                a2 += hv.x * w0.z + hv.y * w1v.z + hv.z * w2v.z + hv.w * w3v.z;
                a3 += hv.x * w0.w + hv.y * w1v.w + hv.z * w2v.w + hv.w * w3v.w;
            }
            const float4 bb = *(const float4*)(h_b2 + o0);
            float4 res;
            res.x = fmaxf(a0 + bb.x, 0.f);
            res.y = fmaxf(a1 + bb.y, 0.f);
            res.z = fmaxf(a2 + bb.z, 0.f);
            res.w = fmaxf(a3 + bb.w, 0.f);
            *(float4*)(&sB[r * 36 + o0]) = res;
        }
    }
    __syncthreads();

    // ---------------- Phase A3: hero layer 3 (32 -> 16, linear) ----------------
    {
        const int slot = tid >> 2;        // 0..63
        const int sub  = tid & 3;
        const int o0 = sub << 2;
        for (int r = slot; r < NROWS; r += 64) {
            float a0 = 0.f, a1 = 0.f, a2 = 0.f, a3 = 0.f;
            #pragma unroll
            for (int k = 0; k < 32; k += 4) {
                const float4 hv = *(const float4*)(&sB[r * 36 + k]);
                const float4 w0 = *(const float4*)(h_w3 + (k + 0) * 16 + o0);
                const float4 w1v = *(const float4*)(h_w3 + (k + 1) * 16 + o0);
                const float4 w2v = *(const float4*)(h_w3 + (k + 2) * 16 + o0);
                const float4 w3v = *(const float4*)(h_w3 + (k + 3) * 16 + o0);
                a0 += hv.x * w0.x + hv.y * w1v.x + hv.z * w2v.x + hv.w * w3v.x;
                a1 += hv.x * w0.y + hv.y * w1v.y + hv.z * w2v.y + hv.w * w3v.y;
                a2 += hv.x * w0.z + hv.y * w1v.z + hv.z * w2v.z + hv.w * w3v.z;
                a3 += hv.x * w0.w + hv.y * w1v.w + hv.z * w2v.w + hv.w * w3v.w;
            }
            const float4 bb = *(const float4*)(h_b3 + o0);
            float4 res;
            res.x = a0 + bb.x; res.y = a1 + bb.y; res.z = a2 + bb.z; res.w = a3 + bb.w;
            *(float4*)(&sHO[r * 20 + o0]) = res;
        }
    }
    __syncthreads();

    // ---------------- Phase B: u = ho@cW1[:16], v = ho@cW1[16:] ----------------
    {
        const int slot = tid >> 2;
        const int sub  = tid & 3;
        const int o0 = sub << 2;
        for (int r = slot; r < NROWS; r += 64) {
            float u0 = 0.f, u1 = 0.f, u2 = 0.f, u3 = 0.f;
            float v0 = 0.f, v1 = 0.f, v2 = 0.f, v3 = 0.f;
            #pragma unroll
            for (int k = 0; k < 16; k += 4) {
                const float4 hv = *(const float4*)(&sHO[r * 20 + k]);
                #pragma unroll
                for (int i = 0; i < 4; ++i) {
                    const float hx = (i == 0) ? hv.x : (i == 1) ? hv.y : (i == 2) ? hv.z : hv.w;
                    const float4 wu = *(const float4*)(c_w1 + (k + i) * 16 + o0);
                    const float4 wv = *(const float4*)(c_w1 + (16 + k + i) * 16 + o0);
                    u0 += hx * wu.x; u1 += hx * wu.y; u2 += hx * wu.z; u3 += hx * wu.w;
                    v0 += hx * wv.x; v1 += hx * wv.y; v2 += hx * wv.z; v3 += hx * wv.w;
                }
            }
            *(float4*)(&sA[r * 36 + o0]) = make_float4(u0, u1, u2, u3);
            *(float4*)(&sA[r * 36 + 16 + o0]) = make_float4(v0, v1, v2, v3);
        }
    }
    __syncthreads();

    // ---------------- Phase C: 50 pairs, counter L2/L3 + pool2 ----------------
    for (int t = tid; t < SPB * 50; t += THREADS) {
        const int sample = t / 50;
        const int p = t % 50;
        int i, j;
        if (p < 25) { i = p / 5; j = 5 + (p % 5); }
        else { const int q = p - 25; i = 5 + q / 5; j = q % 5; }
        const float* ur = &sA[(sample * 10 + i) * 36];
        const float* vr = &sA[(sample * 10 + j) * 36 + 16];
        float h1p[16];
        #pragma unroll
        for (int k = 0; k < 16; ++k) h1p[k] = fmaxf(ur[k] + vr[k] + c_b1[k], 0.f);
        float acc[16];
        #pragma unroll
        for (int o = 0; o < 16; ++o) acc[o] = c_b2[o];
        #pragma unroll
        for (int k = 0; k < 16; ++k) {
            const float* wr = c_w2 + k * 16;
            #pragma unroll
            for (int o = 0; o < 16; ++o) acc[o] += h1p[k] * wr[o];
        }
        float c3[8];
        #pragma unroll
        for (int o = 0; o < 8; ++o) c3[o] = c_b3[o];
        #pragma unroll
        for (int k = 0; k < 16; ++k) {
            const float hk = fmaxf(acc[k], 0.f);
            const float* wr = c_w3 + k * 8;
            #pragma unroll
            for (int o = 0; o < 8; ++o) c3[o] += hk * wr[o];
        }
        float* dst = &sB[sample * 200 + p * 4];
        #pragma unroll
        for (int m = 0; m < 4; ++m) dst[m] = fmaxf(c3[2 * m], c3[2 * m + 1]);
    }
    __syncthreads();

    // ---------------- Phase D: max over 25 pairs -> g ----------------
    if (tid < SPB * 8) {
        const int sample = tid >> 3;
        const int half = (tid >> 2) & 1;
        const int m = tid & 3;
        float mx = -1e30f;
        const int pbase = half * 25;
        #pragma unroll
        for (int p = 0; p < 25; ++p)
            mx = fmaxf(mx, sB[sample * 200 + (pbase + p) * 4 + m]);
        sG[sample * 8 + half * 4 + m] = mx;
    }
    __syncthreads();

    // ---------------- Phase E1: team layer 1 (84 -> 64) ----------------
    {
        const int row = tid >> 4;          // 0..15 : sample*2+half
        const int sub = tid & 15;
        const int o0 = sub << 2;
        const int sample = row >> 1;
        const int half = row & 1;
        float a0 = 0.f, a1 = 0.f, a2 = 0.f, a3 = 0.f;
        int k = 0;
        #pragma unroll
        for (int hh = 0; hh < 5; ++hh) {
            const float* hr = &sHO[(sample * 10 + half * 5 + hh) * 20];
            #pragma unroll
            for (int kk = 0; kk < 16; kk += 4) {
                const float4 hv = *(const float4*)(hr + kk);
                #pragma unroll
                for (int i = 0; i < 4; ++i) {
                    const float hx = (i == 0) ? hv.x : (i == 1) ? hv.y : (i == 2) ? hv.z : hv.w;
                    const float4 w = *(const float4*)(t_w1 + (k + kk + i) * 64 + o0);
                    a0 += hx * w.x; a1 += hx * w.y; a2 += hx * w.z; a3 += hx * w.w;
                }
            }
            k += 16;
        }
        #pragma unroll
        for (int m = 0; m < 4; ++m) {
            const float gv = sG[sample * 8 + half * 4 + m];
            const float4 w = *(const float4*)(t_w1 + (80 + m) * 64 + o0);
            a0 += gv * w.x; a1 += gv * w.y; a2 += gv * w.z; a3 += gv * w.w;
        }
        const float4 bb = *(const float4*)(t_b1 + o0);
        float4 res;
        res.x = fmaxf(a0 + bb.x, 0.f);
        res.y = fmaxf(a1 + bb.y, 0.f);
        res.z = fmaxf(a2 + bb.z, 0.f);
        res.w = fmaxf(a3 + bb.w, 0.f);
        *(float4*)(&sA[row * 68 + o0]) = res;
    }
    __syncthreads();

    // ---------------- Phase E2: team layer 2 (64 -> 64) ----------------
    {
        const int row = tid >> 4;
        const int sub = tid & 15;
        const int o0 = sub << 2;
        float a0 = 0.f, a1 = 0.f, a2 = 0.f, a3 = 0.f;
        #pragma unroll
        for (int k = 0; k < 64; k += 4) {
            const float4 hv = *(const float4*)(&sA[row * 68 + k]);
            #pragma unroll
            for (int i = 0; i < 4; ++i) {
                const float hx = (i == 0) ? hv.x : (i == 1) ? hv.y : (i == 2) ? hv.z : hv.w;
                const float4 w = *(const float4*)(t_w2 + (k + i) * 64 + o0);
                a0 += hx * w.x; a1 += hx * w.y; a2 += hx * w.z; a3 += hx * w.w;
            }
        }
        const float4 bb = *(const float4*)(t_b2 + o0);
        float4 res;
        res.x = fmaxf(a0 + bb.x, 0.f);
        res.y = fmaxf(a1 + bb.y, 0.f);
        res.z = fmaxf(a2 + bb.z, 0.f);
        res.w = fmaxf(a3 + bb.w, 0.f);
        *(float4*)(&sA[1088 + row * 68 + o0]) = res;
    }
    __syncthreads();

    // ---------------- Phase E3: team layer 3 (64 -> 16, linear) ----------------
    {
        const int row = tid >> 4;          // 0..15
        const int o = tid & 15;
        const int sample = row >> 1;
        const int half = row & 1;
        float a = t_b3[o];
        #pragma unroll
        for (int k = 0; k < 64; ++k)
            a += sA[1088 + row * 68 + k] * t_w3[k * 16 + o];
        sT[sample * 32 + half * 16 + o] = a;
    }
    __syncthreads();

    // ---------------- Phase F: final MLP (32 -> 16 -> 16 -> 2) + softmax ----------------
    if (tid < SPB * 16) {
        const int sample = tid >> 4;
        const int o = tid & 15;
        float a = f_b1[o];
        #pragma unroll
        for (int k = 0; k < 32; ++k)
            a += sT[sample * 32 + k] * f_w1[k * 16 + o];
        sF1[sample * 16 + o] = fmaxf(a, 0.f);
    }
    __syncthreads();
    if (tid < SPB * 16) {
        const int sample = tid >> 4;
        const int o = tid & 15;
        float a = f_b2[o];
        #pragma unroll
        for (int k = 0; k < 16; ++k)
            a += sF1[sample * 16 + k] * f_w2[k * 16 + o];
        sF2[sample * 16 + o] = fmaxf(a, 0.f);
    }
    __syncthreads();
    if (tid < SPB) {
        const int sample = tid;
        float l0 = f_b3[0], l1 = f_b3[1];
        #pragma unroll
        for (int k = 0; k < 16; ++k) {
            const float h = sF2[sample * 16 + k];
            l0 += h * f_w3[k * 2];
            l1 += h * f_w3[k * 2 + 1];
        }
        const float e = expf(l1 - l0);
        const float p0 = 1.f / (1.f + e);
        out[(size_t)(s0 + sample) * 2] = p0;
        out[(size_t)(s0 + sample) * 2 + 1] = 1.f - p0;
    }
}

extern "C" void kernel_launch(void* const* d_in, const int* in_sizes, int n_in,
                              void* d_out, int out_size, void* d_ws, size_t ws_size,
                              hipStream_t stream) {
    const float* x    = (const float*)d_in[0];
    const float* h_w1 = (const float*)d_in[1];  const float* h_b1 = (const float*)d_in[2];
    const float* h_w2 = (const float*)d_in[3];  const float* h_b2 = (const float*)d_in[4];
    const float* h_w3 = (const float*)d_in[5];  const float* h_b3 = (const float*)d_in[6];
    const float* c_w1 = (const float*)d_in[7];  const float* c_b1 = (const float*)d_in[8];
    const float* c_w2 = (const float*)d_in[9];  const float* c_b2 = (const float*)d_in[10];
    const float* c_w3 = (const float*)d_in[11]; const float* c_b3 = (const float*)d_in[12];
    const float* t_w1 = (const float*)d_in[13]; const float* t_b1 = (const float*)d_in[14];
    const float* t_w2 = (const float*)d_in[15]; const float* t_b2 = (const float*)d_in[16];
    const float* t_w3 = (const float*)d_in[17]; const float* t_b3 = (const float*)d_in[18];
    const float* f_w1 = (const float*)d_in[19]; const float* f_b1 = (const float*)d_in[20];
    const float* f_w2 = (const float*)d_in[21]; const float* f_b2 = (const float*)d_in[22];
    const float* f_w3 = (const float*)d_in[23]; const float* f_b3 = (const float*)d_in[24];
    float* out = (float*)d_out;

    const int B = 65536;
    const int grid = B / SPB;   // 8192 workgroups
    fused_model_kernel<<<grid, THREADS, 0, stream>>>(
        x, h_w1, h_b1, h_w2, h_b2, h_w3, h_b3,
        c_w1, c_b1, c_w2, c_b2, c_w3, c_b3,
        t_w1, t_b1, t_w2, t_b2, t_w3, t_b3,
        f_w1, f_b1, f_w2, f_b2, f_w3, f_b3,
        out);
}

// Round 2
// 1256.193 us; speedup vs baseline: 1.1527x; 1.1527x over previous
//
#include <hip/hip_runtime.h>
#include <hip/hip_bf16.h>
#include <math.h>

// B=65536 samples. Fused pipeline, round 2:
//  - x staged into LDS in 32-row chunks with fully coalesced float4 streaming
//    (fixes round-1 latency-bound uncoalesced x reads: FETCH 1.18GB -> ~0.37GB)
//  - hero MLP (140->32->32->16) x10 heroes
//  - counter MLP (32->16->16->8) over 50 pairs, factorized layer-1 (u_i + v_j)
//  - maxpool(2) + max over 25 -> g1/g2
//  - team MLP (84->64->64->16) x2, final MLP (32->16->16->2) + softmax
// LDS: 38144B total (sX region aliased by h2/pooled buffers) -> 4 blocks/CU.

#define SPB 8
#define NROWS (SPB * 10)   // 80 hero rows per workgroup
#define THREADS 256

__global__ __launch_bounds__(THREADS, 4) void fused_model_kernel(
    const float* __restrict__ x,
    const float* __restrict__ h_w1, const float* __restrict__ h_b1,
    const float* __restrict__ h_w2, const float* __restrict__ h_b2,
    const float* __restrict__ h_w3, const float* __restrict__ h_b3,
    const float* __restrict__ c_w1, const float* __restrict__ c_b1,
    const float* __restrict__ c_w2, const float* __restrict__ c_b2,
    const float* __restrict__ c_w3, const float* __restrict__ c_b3,
    const float* __restrict__ t_w1, const float* __restrict__ t_b1,
    const float* __restrict__ t_w2, const float* __restrict__ t_b2,
    const float* __restrict__ t_w3, const float* __restrict__ t_b3,
    const float* __restrict__ f_w1, const float* __restrict__ f_b1,
    const float* __restrict__ f_w2, const float* __restrict__ f_b2,
    const float* __restrict__ f_w3, const float* __restrict__ f_b3,
    float* __restrict__ out)
{
    // One LDS arena with hand-placed, phase-disjoint aliasing.
    //   [0,4480)    sX  : x staging chunk (32 rows x 140) -- also aliased as
    //                     sB (h2, 80x36=2880f) and sP (pooled counter, 8x200=1600f)
    //   [4480,7360) sA  : h1 / u|v / team staging (80 x stride36)
    //   [7360,8960) sHO : hero outputs (80 x stride20)
    //   [8960,9024) sG, [9024,9280) sT, [9280,9408) sF1, [9408,9536) sF2
    __shared__ float lds[9536];
    float* const sX  = lds;
    float* const sB  = lds;          // alias (alive only after sX dead)
    float* const sP  = lds;          // alias (alive only after sB dead)
    float* const sA  = lds + 4480;
    float* const sHO = lds + 7360;
    float* const sG  = lds + 8960;
    float* const sT  = lds + 9024;
    float* const sF1 = lds + 9280;
    float* const sF2 = lds + 9408;

    const int tid = threadIdx.x;
    const int wg = blockIdx.x;
    const int s0 = wg * SPB;
    const float* xg = x + (size_t)s0 * 1400;

    // ---------------- Phase A1: hero layer 1 (140 -> 32), chunked ----------------
    {
        const int rl = tid >> 3;          // 0..31 local row
        const int o0 = (tid & 7) << 2;    // 4 outputs per thread
        const float4 bb = *(const float4*)(h_b1 + o0);
        for (int c = 0; c < 3; ++c) {
            const int r0 = c * 32;
            const int nr = (NROWS - r0 < 32) ? (NROWS - r0) : 32;
            // coalesced stage: contiguous float4 stream
            {
                const int nf4 = nr * 35;   // 140 floats = 35 float4 per row
                const float4* src = (const float4*)(xg + r0 * 140);
                float4* dst = (float4*)sX;
                for (int i = tid; i < nf4; i += THREADS) dst[i] = src[i];
            }
            __syncthreads();
            if (rl < nr) {
                const float* px = sX + rl * 140;
                float a0 = 0.f, a1 = 0.f, a2 = 0.f, a3 = 0.f;
                #pragma unroll 5
                for (int k = 0; k < 140; k += 4) {
                    const float4 xv = *(const float4*)(px + k);
                    const float4 w0 = *(const float4*)(h_w1 + (k + 0) * 32 + o0);
                    const float4 w1v = *(const float4*)(h_w1 + (k + 1) * 32 + o0);
                    const float4 w2v = *(const float4*)(h_w1 + (k + 2) * 32 + o0);
                    const float4 w3v = *(const float4*)(h_w1 + (k + 3) * 32 + o0);
                    a0 += xv.x * w0.x + xv.y * w1v.x + xv.z * w2v.x + xv.w * w3v.x;
                    a1 += xv.x * w0.y + xv.y * w1v.y + xv.z * w2v.y + xv.w * w3v.y;
                    a2 += xv.x * w0.z + xv.y * w1v.z + xv.z * w2v.z + xv.w * w3v.z;
                    a3 += xv.x * w0.w + xv.y * w1v.w + xv.z * w2v.w + xv.w * w3v.w;
                }
                float4 res;
                res.x = fmaxf(a0 + bb.x, 0.f);
                res.y = fmaxf(a1 + bb.y, 0.f);
                res.z = fmaxf(a2 + bb.z, 0.f);
                res.w = fmaxf(a3 + bb.w, 0.f);
                *(float4*)(&sA[(r0 + rl) * 36 + o0]) = res;
            }
            __syncthreads();
        }
    }

    // ---------------- Phase A2: hero layer 2 (32 -> 32) ----------------
    {
        const int slot = tid >> 3;
        const int o0 = (tid & 7) << 2;
        const float4 bb = *(const float4*)(h_b2 + o0);
        for (int r = slot; r < NROWS; r += 32) {
            float a0 = 0.f, a1 = 0.f, a2 = 0.f, a3 = 0.f;
            #pragma unroll
            for (int k = 0; k < 32; k += 4) {
                const float4 hv = *(const float4*)(&sA[r * 36 + k]);
                const float4 w0 = *(const float4*)(h_w2 + (k + 0) * 32 + o0);
                const float4 w1v = *(const float4*)(h_w2 + (k + 1) * 32 + o0);
                const float4 w2v = *(const float4*)(h_w2 + (k + 2) * 32 + o0);
                const float4 w3v = *(const float4*)(h_w2 + (k + 3) * 32 + o0);
                a0 += hv.x * w0.x + hv.y * w1v.x + hv.z * w2v.x + hv.w * w3v.x;
                a1 += hv.x * w0.y + hv.y * w1v.y + hv.z * w2v.y + hv.w * w3v.y;
                a2 += hv.x * w0.z + hv.y * w1v.z + hv.z * w2v.z + hv.w * w3v.z;
                a3 += hv.x * w0.w + hv.y * w1v.w + hv.z * w2v.w + hv.w * w3v.w;
            }
            float4 res;
            res.x = fmaxf(a0 + bb.x, 0.f);
            res.y = fmaxf(a1 + bb.y, 0.f);
            res.z = fmaxf(a2 + bb.z, 0.f);
            res.w = fmaxf(a3 + bb.w, 0.f);
            *(float4*)(&sB[r * 36 + o0]) = res;
        }
    }
    __syncthreads();

    // ---------------- Phase A3: hero layer 3 (32 -> 16, linear) ----------------
    {
        const int slot = tid >> 2;
        const int o0 = (tid & 3) << 2;
        const float4 bb = *(const float4*)(h_b3 + o0);
        for (int r = slot; r < NROWS; r += 64) {
            float a0 = 0.f, a1 = 0.f, a2 = 0.f, a3 = 0.f;
            #pragma unroll
            for (int k = 0; k < 32; k += 4) {
                const float4 hv = *(const float4*)(&sB[r * 36 + k]);
                const float4 w0 = *(const float4*)(h_w3 + (k + 0) * 16 + o0);
                const float4 w1v = *(const float4*)(h_w3 + (k + 1) * 16 + o0);
                const float4 w2v = *(const float4*)(h_w3 + (k + 2) * 16 + o0);
                const float4 w3v = *(const float4*)(h_w3 + (k + 3) * 16 + o0);
                a0 += hv.x * w0.x + hv.y * w1v.x + hv.z * w2v.x + hv.w * w3v.x;
                a1 += hv.x * w0.y + hv.y * w1v.y + hv.z * w2v.y + hv.w * w3v.y;
                a2 += hv.x * w0.z + hv.y * w1v.z + hv.z * w2v.z + hv.w * w3v.z;
                a3 += hv.x * w0.w + hv.y * w1v.w + hv.z * w2v.w + hv.w * w3v.w;
            }
            float4 res;
            res.x = a0 + bb.x; res.y = a1 + bb.y; res.z = a2 + bb.z; res.w = a3 + bb.w;
            *(float4*)(&sHO[r * 20 + o0]) = res;
        }
    }
    __syncthreads();

    // ---------------- Phase B: u = ho@cW1[:16], v = ho@cW1[16:] ----------------
    {
        const int slot = tid >> 2;
        const int o0 = (tid & 3) << 2;
        for (int r = slot; r < NROWS; r += 64) {
            float u0 = 0.f, u1 = 0.f, u2 = 0.f, u3 = 0.f;
            float v0 = 0.f, v1 = 0.f, v2 = 0.f, v3 = 0.f;
            #pragma unroll
            for (int k = 0; k < 16; k += 4) {
                const float4 hv = *(const float4*)(&sHO[r * 20 + k]);
                #pragma unroll
                for (int i = 0; i < 4; ++i) {
                    const float hx = (i == 0) ? hv.x : (i == 1) ? hv.y : (i == 2) ? hv.z : hv.w;
                    const float4 wu = *(const float4*)(c_w1 + (k + i) * 16 + o0);
                    const float4 wv = *(const float4*)(c_w1 + (16 + k + i) * 16 + o0);
                    u0 += hx * wu.x; u1 += hx * wu.y; u2 += hx * wu.z; u3 += hx * wu.w;
                    v0 += hx * wv.x; v1 += hx * wv.y; v2 += hx * wv.z; v3 += hx * wv.w;
                }
            }
            *(float4*)(&sA[r * 36 + o0]) = make_float4(u0, u1, u2, u3);
            *(float4*)(&sA[r * 36 + 16 + o0]) = make_float4(v0, v1, v2, v3);
        }
    }
    __syncthreads();

    // ---------------- Phase C: 50 pairs, counter L2/L3 + pool2 ----------------
    for (int t = tid; t < SPB * 50; t += THREADS) {
        const int sample = t / 50;
        const int p = t % 50;
        int i, j;
        if (p < 25) { i = p / 5; j = 5 + (p % 5); }
        else { const int q = p - 25; i = 5 + q / 5; j = q % 5; }
        const float* ur = &sA[(sample * 10 + i) * 36];
        const float* vr = &sA[(sample * 10 + j) * 36 + 16];
        float h1p[16];
        #pragma unroll
        for (int k = 0; k < 16; ++k) h1p[k] = fmaxf(ur[k] + vr[k] + c_b1[k], 0.f);
        float acc[16];
        #pragma unroll
        for (int o = 0; o < 16; ++o) acc[o] = c_b2[o];
        #pragma unroll
        for (int k = 0; k < 16; ++k) {
            const float* wr = c_w2 + k * 16;
            #pragma unroll
            for (int o = 0; o < 16; ++o) acc[o] += h1p[k] * wr[o];
        }
        float c3[8];
        #pragma unroll
        for (int o = 0; o < 8; ++o) c3[o] = c_b3[o];
        #pragma unroll
        for (int k = 0; k < 16; ++k) {
            const float hk = fmaxf(acc[k], 0.f);
            const float* wr = c_w3 + k * 8;
            #pragma unroll
            for (int o = 0; o < 8; ++o) c3[o] += hk * wr[o];
        }
        float* dst = &sP[sample * 200 + p * 4];
        #pragma unroll
        for (int m = 0; m < 4; ++m) dst[m] = fmaxf(c3[2 * m], c3[2 * m + 1]);
    }
    __syncthreads();

    // ---------------- Phase D: max over 25 pairs -> g ----------------
    if (tid < SPB * 8) {
        const int sample = tid >> 3;
        const int half = (tid >> 2) & 1;
        const int m = tid & 3;
        float mx = -1e30f;
        const int pbase = half * 25;
        #pragma unroll
        for (int p = 0; p < 25; ++p)
            mx = fmaxf(mx, sP[sample * 200 + (pbase + p) * 4 + m]);
        sG[sample * 8 + half * 4 + m] = mx;
    }
    __syncthreads();

    // ---------------- Phase E1: team layer 1 (84 -> 64) ----------------
    {
        const int row = tid >> 4;          // 0..15 : sample*2+half
        const int o0 = (tid & 15) << 2;
        const int sample = row >> 1;
        const int half = row & 1;
        float a0 = 0.f, a1 = 0.f, a2 = 0.f, a3 = 0.f;
        int k = 0;
        #pragma unroll
        for (int hh = 0; hh < 5; ++hh) {
            const float* hr = &sHO[(sample * 10 + half * 5 + hh) * 20];
            #pragma unroll
            for (int kk = 0; kk < 16; kk += 4) {
                const float4 hv = *(const float4*)(hr + kk);
                #pragma unroll
                for (int i = 0; i < 4; ++i) {
                    const float hx = (i == 0) ? hv.x : (i == 1) ? hv.y : (i == 2) ? hv.z : hv.w;
                    const float4 w = *(const float4*)(t_w1 + (k + kk + i) * 64 + o0);
                    a0 += hx * w.x; a1 += hx * w.y; a2 += hx * w.z; a3 += hx * w.w;
                }
            }
            k += 16;
        }
        #pragma unroll
        for (int m = 0; m < 4; ++m) {
            const float gv = sG[sample * 8 + half * 4 + m];
            const float4 w = *(const float4*)(t_w1 + (80 + m) * 64 + o0);
            a0 += gv * w.x; a1 += gv * w.y; a2 += gv * w.z; a3 += gv * w.w;
        }
        const float4 bb = *(const float4*)(t_b1 + o0);
        float4 res;
        res.x = fmaxf(a0 + bb.x, 0.f);
        res.y = fmaxf(a1 + bb.y, 0.f);
        res.z = fmaxf(a2 + bb.z, 0.f);
        res.w = fmaxf(a3 + bb.w, 0.f);
        *(float4*)(&sA[row * 68 + o0]) = res;
    }
    __syncthreads();

    // ---------------- Phase E2: team layer 2 (64 -> 64) ----------------
    {
        const int row = tid >> 4;
        const int o0 = (tid & 15) << 2;
        float a0 = 0.f, a1 = 0.f, a2 = 0.f, a3 = 0.f;
        #pragma unroll
        for (int k = 0; k < 64; k += 4) {
            const float4 hv = *(const float4*)(&sA[row * 68 + k]);
            #pragma unroll
            for (int i = 0; i < 4; ++i) {
                const float hx = (i == 0) ? hv.x : (i == 1) ? hv.y : (i == 2) ? hv.z : hv.w;
                const float4 w = *(const float4*)(t_w2 + (k + i) * 64 + o0);
                a0 += hx * w.x; a1 += hx * w.y; a2 += hx * w.z; a3 += hx * w.w;
            }
        }
        const float4 bb = *(const float4*)(t_b2 + o0);
        float4 res;
        res.x = fmaxf(a0 + bb.x, 0.f);
        res.y = fmaxf(a1 + bb.y, 0.f);
        res.z = fmaxf(a2 + bb.z, 0.f);
        res.w = fmaxf(a3 + bb.w, 0.f);
        *(float4*)(&sA[1088 + row * 68 + o0]) = res;
    }
    __syncthreads();

    // ---------------- Phase E3: team layer 3 (64 -> 16, linear) ----------------
    {
        const int row = tid >> 4;          // 0..15
        const int o = tid & 15;
        const int sample = row >> 1;
        const int half = row & 1;
        float a = t_b3[o];
        #pragma unroll
        for (int k = 0; k < 64; ++k)
            a += sA[1088 + row * 68 + k] * t_w3[k * 16 + o];
        sT[sample * 32 + half * 16 + o] = a;
    }
    __syncthreads();

    // ---------------- Phase F: final MLP (32 -> 16 -> 16 -> 2) + softmax ----------------
    if (tid < SPB * 16) {
        const int sample = tid >> 4;
        const int o = tid & 15;
        float a = f_b1[o];
        #pragma unroll
        for (int k = 0; k < 32; ++k)
            a += sT[sample * 32 + k] * f_w1[k * 16 + o];
        sF1[sample * 16 + o] = fmaxf(a, 0.f);
    }
    __syncthreads();
    if (tid < SPB * 16) {
        const int sample = tid >> 4;
        const int o = tid & 15;
        float a = f_b2[o];
        #pragma unroll
        for (int k = 0; k < 16; ++k)
            a += sF1[sample * 16 + k] * f_w2[k * 16 + o];
        sF2[sample * 16 + o] = fmaxf(a, 0.f);
    }
    __syncthreads();
    if (tid < SPB) {
        const int sample = tid;
        float l0 = f_b3[0], l1 = f_b3[1];
        #pragma unroll
        for (int k = 0; k < 16; ++k) {
            const float h = sF2[sample * 16 + k];
            l0 += h * f_w3[k * 2];
            l1 += h * f_w3[k * 2 + 1];
        }
        const float e = expf(l1 - l0);
        const float p0 = 1.f / (1.f + e);
        out[(size_t)(s0 + sample) * 2] = p0;
        out[(size_t)(s0 + sample) * 2 + 1] = 1.f - p0;
    }
}

extern "C" void kernel_launch(void* const* d_in, const int* in_sizes, int n_in,
                              void* d_out, int out_size, void* d_ws, size_t ws_size,
                              hipStream_t stream) {
    const float* x    = (const float*)d_in[0];
    const float* h_w1 = (const float*)d_in[1];  const float* h_b1 = (const float*)d_in[2];
    const float* h_w2 = (const float*)d_in[3];  const float* h_b2 = (const float*)d_in[4];
    const float* h_w3 = (const float*)d_in[5];  const float* h_b3 = (const float*)d_in[6];
    const float* c_w1 = (const float*)d_in[7];  const float* c_b1 = (const float*)d_in[8];
    const float* c_w2 = (const float*)d_in[9];  const float* c_b2 = (const float*)d_in[10];
    const float* c_w3 = (const float*)d_in[11]; const float* c_b3 = (const float*)d_in[12];
    const float* t_w1 = (const float*)d_in[13]; const float* t_b1 = (const float*)d_in[14];
    const float* t_w2 = (const float*)d_in[15]; const float* t_b2 = (const float*)d_in[16];
    const float* t_w3 = (const float*)d_in[17]; const float* t_b3 = (const float*)d_in[18];
    const float* f_w1 = (const float*)d_in[19]; const float* f_b1 = (const float*)d_in[20];
    const float* f_w2 = (const float*)d_in[21]; const float* f_b2 = (const float*)d_in[22];
    const float* f_w3 = (const float*)d_in[23]; const float* f_b3 = (const float*)d_in[24];
    float* out = (float*)d_out;

    const int B = 65536;
    const int grid = B / SPB;   // 8192 workgroups
    fused_model_kernel<<<grid, THREADS, 0, stream>>>(
        x, h_w1, h_b1, h_w2, h_b2, h_w3, h_b3,
        c_w1, c_b1, c_w2, c_b2, c_w3, c_b3,
        t_w1, t_b1, t_w2, t_b2, t_w3, t_b3,
        f_w1, f_b1, f_w2, f_b2, f_w3, f_b3,
        out);
}

// Round 3
// 756.840 us; speedup vs baseline: 1.9132x; 1.6598x over previous
//
#include <hip/hip_runtime.h>
#include <hip/hip_bf16.h>
#include <math.h>

// B=65536 samples. Fused pipeline, round 3:
//  Round-2 diagnosis: WRITE_SIZE 1.79GB vs 512KB legitimate output writes
//  -> register-spill scratch traffic dominates runtime.
//  Fixes: (1) __launch_bounds__(256,2) so the allocator isn't starved,
//         (2) phase C restructured o-blocked (peak live regs ~33 not ~45),
//         (3) unroll pinned low in A1, (4) LDS arena 31744B (5 blocks/CU).

#define SPB 8
#define NROWS (SPB * 10)   // 80 hero rows per workgroup
#define THREADS 256

__global__ __launch_bounds__(THREADS, 2) void fused_model_kernel(
    const float* __restrict__ x,
    const float* __restrict__ h_w1, const float* __restrict__ h_b1,
    const float* __restrict__ h_w2, const float* __restrict__ h_b2,
    const float* __restrict__ h_w3, const float* __restrict__ h_b3,
    const float* __restrict__ c_w1, const float* __restrict__ c_b1,
    const float* __restrict__ c_w2, const float* __restrict__ c_b2,
    const float* __restrict__ c_w3, const float* __restrict__ c_b3,
    const float* __restrict__ t_w1, const float* __restrict__ t_b1,
    const float* __restrict__ t_w2, const float* __restrict__ t_b2,
    const float* __restrict__ t_w3, const float* __restrict__ t_b3,
    const float* __restrict__ f_w1, const float* __restrict__ f_b1,
    const float* __restrict__ f_w2, const float* __restrict__ f_b2,
    const float* __restrict__ f_w3, const float* __restrict__ f_b3,
    float* __restrict__ out)
{
    // LDS arena, phase-disjoint aliasing (floats):
    //  [0,2880)     sX(part)/sB(h2, A2..A3)/sP(pooled, C..D)
    //  [2880,4480)  sX(part)/sHO (written A3, read through E1)
    //  [4480,7360)  sA : h1 (A1..A2) / u|v (B..C) / team staging (E1..E3)
    //  [7360,7424) sG  [7424,7680) sT  [7680,7808) sF1  [7808,7936) sF2
    __shared__ float lds[7936];
    float* const sX  = lds;          // 4480 during A1 staging
    float* const sB  = lds;          // 2880, alive A2..A3
    float* const sP  = lds;          // 1600, alive C..D
    float* const sHO = lds + 2880;   // 1600, alive A3..E1
    float* const sA  = lds + 4480;   // 2880
    float* const sG  = lds + 7360;
    float* const sT  = lds + 7424;
    float* const sF1 = lds + 7680;
    float* const sF2 = lds + 7808;

    const int tid = threadIdx.x;
    const int wg = blockIdx.x;
    const int s0 = wg * SPB;
    const float* xg = x + (size_t)s0 * 1400;

    // ---------------- Phase A1: hero layer 1 (140 -> 32), chunked ----------------
    {
        const int rl = tid >> 3;          // 0..31 local row
        const int o0 = (tid & 7) << 2;    // 4 outputs per thread
        const float4 bb = *(const float4*)(h_b1 + o0);
        for (int c = 0; c < 3; ++c) {
            const int r0 = c * 32;
            const int nr = (NROWS - r0 < 32) ? (NROWS - r0) : 32;
            {   // coalesced stage: contiguous float4 stream
                const int nf4 = nr * 35;
                const float4* src = (const float4*)(xg + r0 * 140);
                float4* dst = (float4*)sX;
                for (int i = tid; i < nf4; i += THREADS) dst[i] = src[i];
            }
            __syncthreads();
            if (rl < nr) {
                const float* px = sX + rl * 140;
                float a0 = 0.f, a1 = 0.f, a2 = 0.f, a3 = 0.f;
                #pragma unroll 2
                for (int k = 0; k < 140; k += 4) {
                    const float4 xv = *(const float4*)(px + k);
                    const float4 w0 = *(const float4*)(h_w1 + (k + 0) * 32 + o0);
                    const float4 w1v = *(const float4*)(h_w1 + (k + 1) * 32 + o0);
                    const float4 w2v = *(const float4*)(h_w1 + (k + 2) * 32 + o0);
                    const float4 w3v = *(const float4*)(h_w1 + (k + 3) * 32 + o0);
                    a0 += xv.x * w0.x + xv.y * w1v.x + xv.z * w2v.x + xv.w * w3v.x;
                    a1 += xv.x * w0.y + xv.y * w1v.y + xv.z * w2v.y + xv.w * w3v.y;
                    a2 += xv.x * w0.z + xv.y * w1v.z + xv.z * w2v.z + xv.w * w3v.z;
                    a3 += xv.x * w0.w + xv.y * w1v.w + xv.z * w2v.w + xv.w * w3v.w;
                }
                float4 res;
                res.x = fmaxf(a0 + bb.x, 0.f);
                res.y = fmaxf(a1 + bb.y, 0.f);
                res.z = fmaxf(a2 + bb.z, 0.f);
                res.w = fmaxf(a3 + bb.w, 0.f);
                *(float4*)(&sA[(r0 + rl) * 36 + o0]) = res;
            }
            __syncthreads();
        }
    }

    // ---------------- Phase A2: hero layer 2 (32 -> 32) ----------------
    {
        const int slot = tid >> 3;
        const int o0 = (tid & 7) << 2;
        const float4 bb = *(const float4*)(h_b2 + o0);
        for (int r = slot; r < NROWS; r += 32) {
            float a0 = 0.f, a1 = 0.f, a2 = 0.f, a3 = 0.f;
            #pragma unroll 2
            for (int k = 0; k < 32; k += 4) {
                const float4 hv = *(const float4*)(&sA[r * 36 + k]);
                const float4 w0 = *(const float4*)(h_w2 + (k + 0) * 32 + o0);
                const float4 w1v = *(const float4*)(h_w2 + (k + 1) * 32 + o0);
                const float4 w2v = *(const float4*)(h_w2 + (k + 2) * 32 + o0);
                const float4 w3v = *(const float4*)(h_w2 + (k + 3) * 32 + o0);
                a0 += hv.x * w0.x + hv.y * w1v.x + hv.z * w2v.x + hv.w * w3v.x;
                a1 += hv.x * w0.y + hv.y * w1v.y + hv.z * w2v.y + hv.w * w3v.y;
                a2 += hv.x * w0.z + hv.y * w1v.z + hv.z * w2v.z + hv.w * w3v.z;
                a3 += hv.x * w0.w + hv.y * w1v.w + hv.z * w2v.w + hv.w * w3v.w;
            }
            float4 res;
            res.x = fmaxf(a0 + bb.x, 0.f);
            res.y = fmaxf(a1 + bb.y, 0.f);
            res.z = fmaxf(a2 + bb.z, 0.f);
            res.w = fmaxf(a3 + bb.w, 0.f);
            *(float4*)(&sB[r * 36 + o0]) = res;
        }
    }
    __syncthreads();

    // ---------------- Phase A3: hero layer 3 (32 -> 16, linear) ----------------
    {
        const int slot = tid >> 2;
        const int o0 = (tid & 3) << 2;
        const float4 bb = *(const float4*)(h_b3 + o0);
        for (int r = slot; r < NROWS; r += 64) {
            float a0 = 0.f, a1 = 0.f, a2 = 0.f, a3 = 0.f;
            #pragma unroll 2
            for (int k = 0; k < 32; k += 4) {
                const float4 hv = *(const float4*)(&sB[r * 36 + k]);
                const float4 w0 = *(const float4*)(h_w3 + (k + 0) * 16 + o0);
                const float4 w1v = *(const float4*)(h_w3 + (k + 1) * 16 + o0);
                const float4 w2v = *(const float4*)(h_w3 + (k + 2) * 16 + o0);
                const float4 w3v = *(const float4*)(h_w3 + (k + 3) * 16 + o0);
                a0 += hv.x * w0.x + hv.y * w1v.x + hv.z * w2v.x + hv.w * w3v.x;
                a1 += hv.x * w0.y + hv.y * w1v.y + hv.z * w2v.y + hv.w * w3v.y;
                a2 += hv.x * w0.z + hv.y * w1v.z + hv.z * w2v.z + hv.w * w3v.z;
                a3 += hv.x * w0.w + hv.y * w1v.w + hv.z * w2v.w + hv.w * w3v.w;
            }
            float4 res;
            res.x = a0 + bb.x; res.y = a1 + bb.y; res.z = a2 + bb.z; res.w = a3 + bb.w;
            *(float4*)(&sHO[r * 20 + o0]) = res;
        }
    }
    __syncthreads();

    // ---------------- Phase B: u = ho@cW1[:16], v = ho@cW1[16:] ----------------
    {
        const int slot = tid >> 2;
        const int o0 = (tid & 3) << 2;
        for (int r = slot; r < NROWS; r += 64) {
            float u0 = 0.f, u1 = 0.f, u2 = 0.f, u3 = 0.f;
            float v0 = 0.f, v1 = 0.f, v2 = 0.f, v3 = 0.f;
            #pragma unroll 2
            for (int k = 0; k < 16; k += 4) {
                const float4 hv = *(const float4*)(&sHO[r * 20 + k]);
                #pragma unroll
                for (int i = 0; i < 4; ++i) {
                    const float hx = (i == 0) ? hv.x : (i == 1) ? hv.y : (i == 2) ? hv.z : hv.w;
                    const float4 wu = *(const float4*)(c_w1 + (k + i) * 16 + o0);
                    const float4 wv = *(const float4*)(c_w1 + (16 + k + i) * 16 + o0);
                    u0 += hx * wu.x; u1 += hx * wu.y; u2 += hx * wu.z; u3 += hx * wu.w;
                    v0 += hx * wv.x; v1 += hx * wv.y; v2 += hx * wv.z; v3 += hx * wv.w;
                }
            }
            *(float4*)(&sA[r * 36 + o0]) = make_float4(u0, u1, u2, u3);
            *(float4*)(&sA[r * 36 + 16 + o0]) = make_float4(v0, v1, v2, v3);
        }
    }
    __syncthreads();

    // ------- Phase C: 50 pairs, counter L2/L3 + pool2 (o-blocked, low regs) -------
    for (int t = tid; t < SPB * 50; t += THREADS) {
        const int sample = t / 50;
        const int p = t % 50;
        int i, j;
        if (p < 25) { i = p / 5; j = 5 + (p % 5); }
        else { const int q = p - 25; i = 5 + q / 5; j = q % 5; }
        const float* ur = &sA[(sample * 10 + i) * 36];
        const float* vr = &sA[(sample * 10 + j) * 36 + 16];
        float h1p[16];
        #pragma unroll
        for (int k = 0; k < 16; ++k) h1p[k] = fmaxf(ur[k] + vr[k] + c_b1[k], 0.f);
        float c3[8];
        #pragma unroll
        for (int m = 0; m < 8; ++m) c3[m] = c_b3[m];
        #pragma unroll
        for (int ob = 0; ob < 2; ++ob) {
            float acc[8];
            #pragma unroll
            for (int oo = 0; oo < 8; ++oo) acc[oo] = c_b2[ob * 8 + oo];
            #pragma unroll
            for (int k = 0; k < 16; ++k) {
                const float hk = h1p[k];
                #pragma unroll
                for (int oo = 0; oo < 8; ++oo)
                    acc[oo] += hk * c_w2[k * 16 + ob * 8 + oo];
            }
            #pragma unroll
            for (int oo = 0; oo < 8; ++oo) {
                const float hv = fmaxf(acc[oo], 0.f);
                const int o = ob * 8 + oo;
                #pragma unroll
                for (int m = 0; m < 8; ++m)
                    c3[m] += hv * c_w3[o * 8 + m];
            }
        }
        float* dst = &sP[sample * 200 + p * 4];
        #pragma unroll
        for (int m = 0; m < 4; ++m) dst[m] = fmaxf(c3[2 * m], c3[2 * m + 1]);
    }
    __syncthreads();

    // ---------------- Phase D: max over 25 pairs -> g ----------------
    if (tid < SPB * 8) {
        const int sample = tid >> 3;
        const int half = (tid >> 2) & 1;
        const int m = tid & 3;
        float mx = -1e30f;
        const int pbase = half * 25;
        #pragma unroll
        for (int p = 0; p < 25; ++p)
            mx = fmaxf(mx, sP[sample * 200 + (pbase + p) * 4 + m]);
        sG[sample * 8 + half * 4 + m] = mx;
    }
    __syncthreads();

    // ---------------- Phase E1: team layer 1 (84 -> 64) ----------------
    {
        const int row = tid >> 4;          // 0..15 : sample*2+half
        const int o0 = (tid & 15) << 2;
        const int sample = row >> 1;
        const int half = row & 1;
        float a0 = 0.f, a1 = 0.f, a2 = 0.f, a3 = 0.f;
        int k = 0;
        for (int hh = 0; hh < 5; ++hh) {
            const float* hr = &sHO[(sample * 10 + half * 5 + hh) * 20];
            #pragma unroll 2
            for (int kk = 0; kk < 16; kk += 4) {
                const float4 hv = *(const float4*)(hr + kk);
                #pragma unroll
                for (int i = 0; i < 4; ++i) {
                    const float hx = (i == 0) ? hv.x : (i == 1) ? hv.y : (i == 2) ? hv.z : hv.w;
                    const float4 w = *(const float4*)(t_w1 + (k + kk + i) * 64 + o0);
                    a0 += hx * w.x; a1 += hx * w.y; a2 += hx * w.z; a3 += hx * w.w;
                }
            }
            k += 16;
        }
        #pragma unroll
        for (int m = 0; m < 4; ++m) {
            const float gv = sG[sample * 8 + half * 4 + m];
            const float4 w = *(const float4*)(t_w1 + (80 + m) * 64 + o0);
            a0 += gv * w.x; a1 += gv * w.y; a2 += gv * w.z; a3 += gv * w.w;
        }
        const float4 bb = *(const float4*)(t_b1 + o0);
        float4 res;
        res.x = fmaxf(a0 + bb.x, 0.f);
        res.y = fmaxf(a1 + bb.y, 0.f);
        res.z = fmaxf(a2 + bb.z, 0.f);
        res.w = fmaxf(a3 + bb.w, 0.f);
        *(float4*)(&sA[row * 68 + o0]) = res;
    }
    __syncthreads();

    // ---------------- Phase E2: team layer 2 (64 -> 64) ----------------
    {
        const int row = tid >> 4;
        const int o0 = (tid & 15) << 2;
        float a0 = 0.f, a1 = 0.f, a2 = 0.f, a3 = 0.f;
        #pragma unroll 2
        for (int k = 0; k < 64; k += 4) {
            const float4 hv = *(const float4*)(&sA[row * 68 + k]);
            #pragma unroll
            for (int i = 0; i < 4; ++i) {
                const float hx = (i == 0) ? hv.x : (i == 1) ? hv.y : (i == 2) ? hv.z : hv.w;
                const float4 w = *(const float4*)(t_w2 + (k + i) * 64 + o0);
                a0 += hx * w.x; a1 += hx * w.y; a2 += hx * w.z; a3 += hx * w.w;
            }
        }
        const float4 bb = *(const float4*)(t_b2 + o0);
        float4 res;
        res.x = fmaxf(a0 + bb.x, 0.f);
        res.y = fmaxf(a1 + bb.y, 0.f);
        res.z = fmaxf(a2 + bb.z, 0.f);
        res.w = fmaxf(a3 + bb.w, 0.f);
        *(float4*)(&sA[1088 + row * 68 + o0]) = res;
    }
    __syncthreads();

    // ---------------- Phase E3: team layer 3 (64 -> 16, linear) ----------------
    {
        const int row = tid >> 4;
        const int o = tid & 15;
        const int sample = row >> 1;
        const int half = row & 1;
        float a = t_b3[o];
        #pragma unroll 4
        for (int k = 0; k < 64; ++k)
            a += sA[1088 + row * 68 + k] * t_w3[k * 16 + o];
        sT[sample * 32 + half * 16 + o] = a;
    }
    __syncthreads();

    // ---------------- Phase F: final MLP (32->16->16->2) + softmax ----------------
    if (tid < SPB * 16) {
        const int sample = tid >> 4;
        const int o = tid & 15;
        float a = f_b1[o];
        #pragma unroll 4
        for (int k = 0; k < 32; ++k)
            a += sT[sample * 32 + k] * f_w1[k * 16 + o];
        sF1[sample * 16 + o] = fmaxf(a, 0.f);
    }
    __syncthreads();
    if (tid < SPB * 16) {
        const int sample = tid >> 4;
        const int o = tid & 15;
        float a = f_b2[o];
        #pragma unroll 4
        for (int k = 0; k < 16; ++k)
            a += sF1[sample * 16 + k] * f_w2[k * 16 + o];
        sF2[sample * 16 + o] = fmaxf(a, 0.f);
    }
    __syncthreads();
    if (tid < SPB) {
        const int sample = tid;
        float l0 = f_b3[0], l1 = f_b3[1];
        #pragma unroll 4
        for (int k = 0; k < 16; ++k) {
            const float h = sF2[sample * 16 + k];
            l0 += h * f_w3[k * 2];
            l1 += h * f_w3[k * 2 + 1];
        }
        const float e = expf(l1 - l0);
        const float p0 = 1.f / (1.f + e);
        out[(size_t)(s0 + sample) * 2] = p0;
        out[(size_t)(s0 + sample) * 2 + 1] = 1.f - p0;
    }
}

extern "C" void kernel_launch(void* const* d_in, const int* in_sizes, int n_in,
                              void* d_out, int out_size, void* d_ws, size_t ws_size,
                              hipStream_t stream) {
    const float* x    = (const float*)d_in[0];
    const float* h_w1 = (const float*)d_in[1];  const float* h_b1 = (const float*)d_in[2];
    const float* h_w2 = (const float*)d_in[3];  const float* h_b2 = (const float*)d_in[4];
    const float* h_w3 = (const float*)d_in[5];  const float* h_b3 = (const float*)d_in[6];
    const float* c_w1 = (const float*)d_in[7];  const float* c_b1 = (const float*)d_in[8];
    const float* c_w2 = (const float*)d_in[9];  const float* c_b2 = (const float*)d_in[10];
    const float* c_w3 = (const float*)d_in[11]; const float* c_b3 = (const float*)d_in[12];
    const float* t_w1 = (const float*)d_in[13]; const float* t_b1 = (const float*)d_in[14];
    const float* t_w2 = (const float*)d_in[15]; const float* t_b2 = (const float*)d_in[16];
    const float* t_w3 = (const float*)d_in[17]; const float* t_b3 = (const float*)d_in[18];
    const float* f_w1 = (const float*)d_in[19]; const float* f_b1 = (const float*)d_in[20];
    const float* f_w2 = (const float*)d_in[21]; const float* f_b2 = (const float*)d_in[22];
    const float* f_w3 = (const float*)d_in[23]; const float* f_b3 = (const float*)d_in[24];
    float* out = (float*)d_out;

    const int B = 65536;
    const int grid = B / SPB;   // 8192 workgroups
    fused_model_kernel<<<grid, THREADS, 0, stream>>>(
        x, h_w1, h_b1, h_w2, h_b2, h_w3, h_b3,
        c_w1, c_b1, c_w2, c_b2, c_w3, c_b3,
        t_w1, t_b1, t_w2, t_b2, t_w3, t_b3,
        f_w1, f_b1, f_w2, f_b2, f_w3, f_b3,
        out);
}

// Round 4
// 718.432 us; speedup vs baseline: 2.0155x; 1.0535x over previous
//
#include <hip/hip_runtime.h>
#include <hip/hip_bf16.h>
#include <math.h>

// Round 4: row-per-lane + wave-uniform (SGPR) weights.
//  - lane owns one hero row end-to-end: h1/h2/ho/u/v in registers, fully
//    unrolled layers; weight indices lane-independent -> s_load + SGPR-FMA.
//  - x staged per-K-chunk into LDS (coalesced float4 global reads, odd-stride
//    conflict-free LDS).
//  - cross-lane intermediates (ho, u/v, team h1/h2) bf16-packed in LDS.
//  - SPB=24 samples/wg (240 rows), 256 threads, LDS 53568B -> 3 wg/CU.

#define THREADS 256
#define SPB 24
#define NB 65536

__device__ __forceinline__ unsigned bfr(float f) {
    unsigned u = __float_as_uint(f);
    return (u + 0x7fffu + ((u >> 16) & 1u)) >> 16;   // RNE to bf16
}
__device__ __forceinline__ unsigned pack_bf(float a, float b) {
    return bfr(a) | (bfr(b) << 16);
}
__device__ __forceinline__ float bf_lo(unsigned u) { return __uint_as_float(u << 16); }
__device__ __forceinline__ float bf_hi(unsigned u) { return __uint_as_float(u & 0xffff0000u); }

__global__ __launch_bounds__(THREADS, 3) void fused_model_kernel(
    const float* __restrict__ x,
    const float* __restrict__ h_w1, const float* __restrict__ h_b1,
    const float* __restrict__ h_w2, const float* __restrict__ h_b2,
    const float* __restrict__ h_w3, const float* __restrict__ h_b3,
    const float* __restrict__ c_w1, const float* __restrict__ c_b1,
    const float* __restrict__ c_w2, const float* __restrict__ c_b2,
    const float* __restrict__ c_w3, const float* __restrict__ c_b3,
    const float* __restrict__ t_w1, const float* __restrict__ t_b1,
    const float* __restrict__ t_w2, const float* __restrict__ t_b2,
    const float* __restrict__ t_w3, const float* __restrict__ t_b3,
    const float* __restrict__ f_w1, const float* __restrict__ f_b1,
    const float* __restrict__ f_w2, const float* __restrict__ f_b2,
    const float* __restrict__ f_w3, const float* __restrict__ f_b3,
    float* __restrict__ out)
{
    // LDS arena: 13392 u32 = 53568 B.
    //  [0,6000)      xT    f32, x K-chunk, 240 rows x stride 25 (A1)
    //  [0,1584)      h1t   u32 bf16x2, 48 rows x 33  (E1..E2, aliases xT)
    //  [1584,3168)   h2t   u32 bf16x2, 48 rows x 33  (E2..E3, aliases xT)
    //  [6000,8160)   ho32  u32 bf16x2, 240 rows x 9  (B..E1)
    //  [8160,12240)  uv32  u32 bf16x2, 240 rows x 17 (B..C)
    //  [8160,8568)   sF1   f32 24x17 (F1..F2, aliases uv32)
    //  [8568,8976)   sF2   f32 24x17 (F2..F3, aliases uv32)
    //  [12240,13200) sPm   f32 24*2*5*4 (C..D)
    //  [12240,13032) sT    f32 24x33 (E3..F1, aliases sPm)
    //  [13200,13392) sG    f32 24x8 (D..E1)
    __shared__ unsigned smem_u[13392];
    float*    const xT   = (float*)smem_u;
    unsigned* const h1t  = smem_u;
    unsigned* const h2t  = smem_u + 1584;
    unsigned* const ho32 = smem_u + 6000;
    unsigned* const uv32 = smem_u + 8160;
    float*    const sF1  = (float*)(smem_u + 8160);
    float*    const sF2  = (float*)(smem_u + 8568);
    float*    const sPm  = (float*)(smem_u + 12240);
    float*    const sT   = (float*)(smem_u + 12240);
    float*    const sG   = (float*)(smem_u + 13200);

    const int tid = threadIdx.x;
    const int wg  = blockIdx.x;
    const int s0  = wg * SPB;
    const int vs  = (NB - s0 < SPB) ? (NB - s0) : SPB;   // valid samples
    const int vr  = vs * 10;                              // valid hero rows
    const float* xg = x + (size_t)s0 * 1400;

    // ============ Phase A1: hero layer 1 (140 -> 32), K-chunked ============
    float acc[32];
    #pragma unroll
    for (int o = 0; o < 32; ++o) acc[o] = h_b1[o];

    for (int c = 0; c < 6; ++c) {
        const int k0 = c * 24;
        const int kc = (c == 5) ? 20 : 24;
        if (tid < vr) {     // stage: coalesced 16B global, odd-stride LDS
            const float* src = xg + tid * 140 + k0;
            float* dst = xT + tid * 25;
            const int nf4 = kc >> 2;
            for (int q = 0; q < nf4; ++q) {
                const float4 v = *(const float4*)(src + q * 4);
                dst[q * 4 + 0] = v.x; dst[q * 4 + 1] = v.y;
                dst[q * 4 + 2] = v.z; dst[q * 4 + 3] = v.w;
            }
        }
        __syncthreads();
        if (tid < vr) {
            const float* xr = xT + tid * 25;
            #pragma unroll 4
            for (int kk = 0; kk < kc; ++kk) {
                const float xk = xr[kk];
                const float* wr = h_w1 + (k0 + kk) * 32;   // uniform -> SGPR
                #pragma unroll
                for (int o = 0; o < 32; ++o) acc[o] = fmaf(xk, wr[o], acc[o]);
            }
        }
        __syncthreads();
    }

    // ====== Phases A2/A3/B: all-register per-lane chain, uniform weights ======
    if (tid < vr) {
        float h1[32];
        #pragma unroll
        for (int o = 0; o < 32; ++o) h1[o] = fmaxf(acc[o], 0.f);

        float a2[32];
        #pragma unroll
        for (int o = 0; o < 32; ++o) a2[o] = h_b2[o];
        #pragma unroll
        for (int k = 0; k < 32; ++k) {
            const float hk = h1[k];
            const float* wr = h_w2 + k * 32;
            #pragma unroll
            for (int o = 0; o < 32; ++o) a2[o] = fmaf(hk, wr[o], a2[o]);
        }
        float h2[32];
        #pragma unroll
        for (int o = 0; o < 32; ++o) h2[o] = fmaxf(a2[o], 0.f);

        float ho[16];
        #pragma unroll
        for (int o = 0; o < 16; ++o) ho[o] = h_b3[o];
        #pragma unroll
        for (int k = 0; k < 32; ++k) {
            const float hk = h2[k];
            const float* wr = h_w3 + k * 16;
            #pragma unroll
            for (int o = 0; o < 16; ++o) ho[o] = fmaf(hk, wr[o], ho[o]);
        }

        float u[16], v[16];
        #pragma unroll
        for (int o = 0; o < 16; ++o) { u[o] = 0.f; v[o] = 0.f; }
        #pragma unroll
        for (int k = 0; k < 16; ++k) {
            const float hk = ho[k];
            const float* wu = c_w1 + k * 16;
            const float* wv = c_w1 + (16 + k) * 16;
            #pragma unroll
            for (int o = 0; o < 16; ++o) {
                u[o] = fmaf(hk, wu[o], u[o]);
                v[o] = fmaf(hk, wv[o], v[o]);
            }
        }

        // cross-lane handoff: bf16-packed
        #pragma unroll
        for (int cc = 0; cc < 8; ++cc)
            ho32[tid * 9 + cc] = pack_bf(ho[2 * cc], ho[2 * cc + 1]);
        #pragma unroll
        for (int cc = 0; cc < 8; ++cc) {
            uv32[tid * 17 + cc]     = pack_bf(u[2 * cc], u[2 * cc + 1]);
            uv32[tid * 17 + 8 + cc] = pack_bf(v[2 * cc], v[2 * cc + 1]);
        }
    }
    __syncthreads();

    // ============ Phase C: 50 pairs, counter L2/L3 + pool2 ============
    // lane = (sample, half, pair-group of 5)
    if (tid < vs * 10) {
        const int s = tid / 10;
        const int t10 = tid % 10;
        const int half = t10 / 5;
        const int pg = t10 % 5;
        float pm0 = -1e30f, pm1 = -1e30f, pm2 = -1e30f, pm3 = -1e30f;
        for (int n = 0; n < 5; ++n) {
            int i, j;
            if (half == 0) { i = pg; j = 5 + n; } else { i = 5 + pg; j = n; }
            const unsigned* ur = uv32 + (s * 10 + i) * 17;
            const unsigned* vrw = uv32 + (s * 10 + j) * 17 + 8;
            float h1p[16];
            #pragma unroll
            for (int cc = 0; cc < 8; ++cc) {
                const unsigned uu = ur[cc], vv = vrw[cc];
                h1p[2 * cc]     = fmaxf(bf_lo(uu) + bf_lo(vv) + c_b1[2 * cc], 0.f);
                h1p[2 * cc + 1] = fmaxf(bf_hi(uu) + bf_hi(vv) + c_b1[2 * cc + 1], 0.f);
            }
            float a[16];
            #pragma unroll
            for (int o = 0; o < 16; ++o) a[o] = c_b2[o];
            #pragma unroll
            for (int k = 0; k < 16; ++k) {
                const float hk = h1p[k];
                const float* wr = c_w2 + k * 16;   // uniform -> SGPR
                #pragma unroll
                for (int o = 0; o < 16; ++o) a[o] = fmaf(hk, wr[o], a[o]);
            }
            float c3[8];
            #pragma unroll
            for (int o = 0; o < 8; ++o) c3[o] = c_b3[o];
            #pragma unroll
            for (int k = 0; k < 16; ++k) {
                const float hk = fmaxf(a[k], 0.f);
                const float* wr = c_w3 + k * 8;
                #pragma unroll
                for (int o = 0; o < 8; ++o) c3[o] = fmaf(hk, wr[o], c3[o]);
            }
            pm0 = fmaxf(pm0, fmaxf(c3[0], c3[1]));
            pm1 = fmaxf(pm1, fmaxf(c3[2], c3[3]));
            pm2 = fmaxf(pm2, fmaxf(c3[4], c3[5]));
            pm3 = fmaxf(pm3, fmaxf(c3[6], c3[7]));
        }
        float* dst = sPm + ((s * 2 + half) * 5 + pg) * 4;
        dst[0] = pm0; dst[1] = pm1; dst[2] = pm2; dst[3] = pm3;
    }
    __syncthreads();

    // ============ Phase D: max over 5 groups -> g ============
    if (tid < vs * 8) {
        const int s = tid >> 3;
        const int r = tid & 7;            // half*4 + m
        const int half = r >> 2, m = r & 3;
        float mx = -1e30f;
        #pragma unroll
        for (int pg = 0; pg < 5; ++pg)
            mx = fmaxf(mx, sPm[((s * 2 + half) * 5 + pg) * 4 + m]);
        sG[s * 8 + r] = mx;
    }
    __syncthreads();

    // ============ Phase E1: team layer 1 (84 -> 64), 4 lanes/row ============
    if (tid < vs * 8) {
        const int s = tid >> 3;
        const int half = (tid >> 2) & 1;
        const int q = tid & 3;
        const int o0 = q * 16;
        float a[16];
        #pragma unroll
        for (int o = 0; o < 16; ++o) a[o] = t_b1[o0 + o];
        for (int h5 = 0; h5 < 5; ++h5) {
            const int row = s * 10 + half * 5 + h5;
            #pragma unroll
            for (int cc = 0; cc < 8; ++cc) {
                const unsigned hv = ho32[row * 9 + cc];
                const float x0 = bf_lo(hv), x1 = bf_hi(hv);
                const int k0 = h5 * 16 + 2 * cc;
                #pragma unroll
                for (int ob = 0; ob < 4; ++ob) {
                    const float4 w0 = *(const float4*)(t_w1 + k0 * 64 + o0 + ob * 4);
                    const float4 w1 = *(const float4*)(t_w1 + (k0 + 1) * 64 + o0 + ob * 4);
                    a[ob * 4 + 0] = fmaf(x0, w0.x, a[ob * 4 + 0]);
                    a[ob * 4 + 1] = fmaf(x0, w0.y, a[ob * 4 + 1]);
                    a[ob * 4 + 2] = fmaf(x0, w0.z, a[ob * 4 + 2]);
                    a[ob * 4 + 3] = fmaf(x0, w0.w, a[ob * 4 + 3]);
                    a[ob * 4 + 0] = fmaf(x1, w1.x, a[ob * 4 + 0]);
                    a[ob * 4 + 1] = fmaf(x1, w1.y, a[ob * 4 + 1]);
                    a[ob * 4 + 2] = fmaf(x1, w1.z, a[ob * 4 + 2]);
                    a[ob * 4 + 3] = fmaf(x1, w1.w, a[ob * 4 + 3]);
                }
            }
        }
        #pragma unroll
        for (int m = 0; m < 4; ++m) {
            const float gv = sG[s * 8 + half * 4 + m];
            #pragma unroll
            for (int ob = 0; ob < 4; ++ob) {
                const float4 w = *(const float4*)(t_w1 + (80 + m) * 64 + o0 + ob * 4);
                a[ob * 4 + 0] = fmaf(gv, w.x, a[ob * 4 + 0]);
                a[ob * 4 + 1] = fmaf(gv, w.y, a[ob * 4 + 1]);
                a[ob * 4 + 2] = fmaf(gv, w.z, a[ob * 4 + 2]);
                a[ob * 4 + 3] = fmaf(gv, w.w, a[ob * 4 + 3]);
            }
        }
        const int row48 = s * 2 + half;
        #pragma unroll
        for (int cc = 0; cc < 8; ++cc)
            h1t[row48 * 33 + q * 8 + cc] =
                pack_bf(fmaxf(a[2 * cc], 0.f), fmaxf(a[2 * cc + 1], 0.f));
    }
    __syncthreads();

    // ============ Phase E2: team layer 2 (64 -> 64) ============
    if (tid < vs * 8) {
        const int s = tid >> 3;
        const int half = (tid >> 2) & 1;
        const int q = tid & 3;
        const int o0 = q * 16;
        const int row48 = s * 2 + half;
        float a[16];
        #pragma unroll
        for (int o = 0; o < 16; ++o) a[o] = t_b2[o0 + o];
        #pragma unroll 8
        for (int cc = 0; cc < 32; ++cc) {
            const unsigned hv = h1t[row48 * 33 + cc];
            const float x0 = bf_lo(hv), x1 = bf_hi(hv);
            #pragma unroll
            for (int ob = 0; ob < 4; ++ob) {
                const float4 w0 = *(const float4*)(t_w2 + (2 * cc) * 64 + o0 + ob * 4);
                const float4 w1 = *(const float4*)(t_w2 + (2 * cc + 1) * 64 + o0 + ob * 4);
                a[ob * 4 + 0] = fmaf(x0, w0.x, a[ob * 4 + 0]);
                a[ob * 4 + 1] = fmaf(x0, w0.y, a[ob * 4 + 1]);
                a[ob * 4 + 2] = fmaf(x0, w0.z, a[ob * 4 + 2]);
                a[ob * 4 + 3] = fmaf(x0, w0.w, a[ob * 4 + 3]);
                a[ob * 4 + 0] = fmaf(x1, w1.x, a[ob * 4 + 0]);
                a[ob * 4 + 1] = fmaf(x1, w1.y, a[ob * 4 + 1]);
                a[ob * 4 + 2] = fmaf(x1, w1.z, a[ob * 4 + 2]);
                a[ob * 4 + 3] = fmaf(x1, w1.w, a[ob * 4 + 3]);
            }
        }
        #pragma unroll
        for (int cc = 0; cc < 8; ++cc)
            h2t[row48 * 33 + q * 8 + cc] =
                pack_bf(fmaxf(a[2 * cc], 0.f), fmaxf(a[2 * cc + 1], 0.f));
    }
    __syncthreads();

    // ============ Phase E3: team layer 3 (64 -> 16, linear) ============
    if (tid < vs * 8) {
        const int s = tid >> 3;
        const int half = (tid >> 2) & 1;
        const int q = tid & 3;
        const int o0 = q * 4;
        const int row48 = s * 2 + half;
        float a0 = t_b3[o0], a1 = t_b3[o0 + 1], a2 = t_b3[o0 + 2], a3 = t_b3[o0 + 3];
        #pragma unroll 8
        for (int cc = 0; cc < 32; ++cc) {
            const unsigned hv = h2t[row48 * 33 + cc];
            const float x0 = bf_lo(hv), x1 = bf_hi(hv);
            const float4 w0 = *(const float4*)(t_w3 + (2 * cc) * 16 + o0);
            const float4 w1 = *(const float4*)(t_w3 + (2 * cc + 1) * 16 + o0);
            a0 = fmaf(x0, w0.x, a0); a1 = fmaf(x0, w0.y, a1);
            a2 = fmaf(x0, w0.z, a2); a3 = fmaf(x0, w0.w, a3);
            a0 = fmaf(x1, w1.x, a0); a1 = fmaf(x1, w1.y, a1);
            a2 = fmaf(x1, w1.z, a2); a3 = fmaf(x1, w1.w, a3);
        }
        float* dst = sT + s * 33 + half * 16 + o0;
        dst[0] = a0; dst[1] = a1; dst[2] = a2; dst[3] = a3;
    }
    __syncthreads();

    // ============ Phase F1: final layer 1 (32 -> 16) ============
    if (tid < vs * 4) {
        const int s = tid >> 2;
        const int q = tid & 3;
        const int o0 = q * 4;
        const float* tr = sT + s * 33;
        float a0 = f_b1[o0], a1 = f_b1[o0 + 1], a2 = f_b1[o0 + 2], a3 = f_b1[o0 + 3];
        #pragma unroll 8
        for (int k = 0; k < 32; ++k) {
            const float hk = tr[k];
            const float4 w = *(const float4*)(f_w1 + k * 16 + o0);
            a0 = fmaf(hk, w.x, a0); a1 = fmaf(hk, w.y, a1);
            a2 = fmaf(hk, w.z, a2); a3 = fmaf(hk, w.w, a3);
        }
        float* dst = sF1 + s * 17 + o0;
        dst[0] = fmaxf(a0, 0.f); dst[1] = fmaxf(a1, 0.f);
        dst[2] = fmaxf(a2, 0.f); dst[3] = fmaxf(a3, 0.f);
    }
    __syncthreads();

    // ============ Phase F2: final layer 2 (16 -> 16) ============
    if (tid < vs * 4) {
        const int s = tid >> 2;
        const int q = tid & 3;
        const int o0 = q * 4;
        const float* fr = sF1 + s * 17;
        float a0 = f_b2[o0], a1 = f_b2[o0 + 1], a2 = f_b2[o0 + 2], a3 = f_b2[o0 + 3];
        #pragma unroll 8
        for (int k = 0; k < 16; ++k) {
            const float hk = fr[k];
            const float4 w = *(const float4*)(f_w2 + k * 16 + o0);
            a0 = fmaf(hk, w.x, a0); a1 = fmaf(hk, w.y, a1);
            a2 = fmaf(hk, w.z, a2); a3 = fmaf(hk, w.w, a3);
        }
        float* dst = sF2 + s * 17 + o0;
        dst[0] = fmaxf(a0, 0.f); dst[1] = fmaxf(a1, 0.f);
        dst[2] = fmaxf(a2, 0.f); dst[3] = fmaxf(a3, 0.f);
    }
    __syncthreads();

    // ============ Phase F3: logits + softmax ============
    if (tid < vs) {
        const float* fr = sF2 + tid * 17;
        float l0 = f_b3[0], l1 = f_b3[1];
        #pragma unroll
        for (int k = 0; k < 16; ++k) {
            const float hk = fr[k];
            l0 = fmaf(hk, f_w3[2 * k], l0);
            l1 = fmaf(hk, f_w3[2 * k + 1], l1);
        }
        const float e = expf(l1 - l0);
        const float p0 = 1.f / (1.f + e);
        out[(size_t)(s0 + tid) * 2]     = p0;
        out[(size_t)(s0 + tid) * 2 + 1] = 1.f - p0;
    }
}

extern "C" void kernel_launch(void* const* d_in, const int* in_sizes, int n_in,
                              void* d_out, int out_size, void* d_ws, size_t ws_size,
                              hipStream_t stream) {
    (void)in_sizes; (void)n_in; (void)d_ws; (void)ws_size; (void)out_size;
    const float* x    = (const float*)d_in[0];
    const float* h_w1 = (const float*)d_in[1];  const float* h_b1 = (const float*)d_in[2];
    const float* h_w2 = (const float*)d_in[3];  const float* h_b2 = (const float*)d_in[4];
    const float* h_w3 = (const float*)d_in[5];  const float* h_b3 = (const float*)d_in[6];
    const float* c_w1 = (const float*)d_in[7];  const float* c_b1 = (const float*)d_in[8];
    const float* c_w2 = (const float*)d_in[9];  const float* c_b2 = (const float*)d_in[10];
    const float* c_w3 = (const float*)d_in[11]; const float* c_b3 = (const float*)d_in[12];
    const float* t_w1 = (const float*)d_in[13]; const float* t_b1 = (const float*)d_in[14];
    const float* t_w2 = (const float*)d_in[15]; const float* t_b2 = (const float*)d_in[16];
    const float* t_w3 = (const float*)d_in[17]; const float* t_b3 = (const float*)d_in[18];
    const float* f_w1 = (const float*)d_in[19]; const float* f_b1 = (const float*)d_in[20];
    const float* f_w2 = (const float*)d_in[21]; const float* f_b2 = (const float*)d_in[22];
    const float* f_w3 = (const float*)d_in[23]; const float* f_b3 = (const float*)d_in[24];
    float* out = (float*)d_out;

    const int grid = (NB + SPB - 1) / SPB;   // 2731 workgroups
    fused_model_kernel<<<grid, THREADS, 0, stream>>>(
        x, h_w1, h_b1, h_w2, h_b2, h_w3, h_b3,
        c_w1, c_b1, c_w2, c_b2, c_w3, c_b3,
        t_w1, t_b1, t_w2, t_b2, t_w3, t_b3,
        f_w1, f_b1, f_w2, f_b2, f_w3, f_b3,
        out);
}

// Round 5
// 559.237 us; speedup vs baseline: 2.5892x; 1.2847x over previous
//
#include <hip/hip_runtime.h>
#include <hip/hip_bf16.h>
#include <math.h>

// Round 5: occupancy + de-staging.
//  Round-4 diagnosis: LDS 53.7KB -> 2 wg/CU (8 waves) -> latency-bound at
//  24% VALUBusy. Fixes:
//  - no x staging: lane streams its own contiguous 560B row (35x float4),
//    zero over-fetch, zero A1 barriers.
//  - LDS arena 30800B -> 5 wg/CU; __launch_bounds__(256,5) (VGPR cap 102).
//  - 6 barriers total (was 18); final MLP merged to one per-sample block.
//  - SPB=25 (250/256 lanes own a hero row).

#define THREADS 256
#define SPB 25
#define NB 65536

__device__ __forceinline__ unsigned bfr(float f) {
    unsigned u = __float_as_uint(f);
    return (u + 0x7fffu + ((u >> 16) & 1u)) >> 16;   // RNE to bf16
}
__device__ __forceinline__ unsigned pack_bf(float a, float b) {
    return bfr(a) | (bfr(b) << 16);
}
__device__ __forceinline__ float bf_lo(unsigned u) { return __uint_as_float(u << 16); }
__device__ __forceinline__ float bf_hi(unsigned u) { return __uint_as_float(u & 0xffff0000u); }

__global__ __launch_bounds__(THREADS, 5) void fused_model_kernel(
    const float* __restrict__ x,
    const float* __restrict__ h_w1, const float* __restrict__ h_b1,
    const float* __restrict__ h_w2, const float* __restrict__ h_b2,
    const float* __restrict__ h_w3, const float* __restrict__ h_b3,
    const float* __restrict__ c_w1, const float* __restrict__ c_b1,
    const float* __restrict__ c_w2, const float* __restrict__ c_b2,
    const float* __restrict__ c_w3, const float* __restrict__ c_b3,
    const float* __restrict__ t_w1, const float* __restrict__ t_b1,
    const float* __restrict__ t_w2, const float* __restrict__ t_b2,
    const float* __restrict__ t_w3, const float* __restrict__ t_b3,
    const float* __restrict__ f_w1, const float* __restrict__ f_b1,
    const float* __restrict__ f_w2, const float* __restrict__ f_b2,
    const float* __restrict__ f_w3, const float* __restrict__ f_b3,
    float* __restrict__ out)
{
    // LDS arena: 7700 u32 = 30800 B.
    //  [0,2250)     ho32 u32 bf16x2, 250 rows x 9   (A..E1)
    //  [2250,6500)  uv32 u32 bf16x2, 250 rows x 17  (A..C)
    //     alias: h1t [2250,3900) 50x33 (E1..E2), h2t [3900,5550) (E2..E3)
    //  [6500,7500)  sPm  f32 25*2*5*4 (C..D);  alias sT f32 25x33 (E3..F)
    //  [7500,7700)  sG   f32 25x8 (D..E1)
    __shared__ unsigned smem_u[7700];
    unsigned* const ho32 = smem_u;
    unsigned* const uv32 = smem_u + 2250;
    unsigned* const h1t  = smem_u + 2250;
    unsigned* const h2t  = smem_u + 3900;
    float*    const sPm  = (float*)(smem_u + 6500);
    float*    const sT   = (float*)(smem_u + 6500);
    float*    const sG   = (float*)(smem_u + 7500);

    const int tid = threadIdx.x;
    const int wg  = blockIdx.x;
    const int s0  = wg * SPB;
    const int vs  = (NB - s0 < SPB) ? (NB - s0) : SPB;
    const int vr  = vs * 10;

    // ===== Phase A: hero chain + u/v, one row per lane, weights in SGPRs =====
    if (tid < vr) {
        const float* xr = x + ((size_t)s0 * 10 + tid) * 140;
        float acc[32];
        #pragma unroll
        for (int o = 0; o < 32; ++o) acc[o] = h_b1[o];
        #pragma unroll 5
        for (int q = 0; q < 35; ++q) {
            const float4 xv = *(const float4*)(xr + q * 4);
            const float* w0 = h_w1 + (q * 4 + 0) * 32;
            const float* w1 = h_w1 + (q * 4 + 1) * 32;
            const float* w2 = h_w1 + (q * 4 + 2) * 32;
            const float* w3 = h_w1 + (q * 4 + 3) * 32;
            #pragma unroll
            for (int o = 0; o < 32; ++o) {
                float a = fmaf(xv.x, w0[o], acc[o]);
                a = fmaf(xv.y, w1[o], a);
                a = fmaf(xv.z, w2[o], a);
                acc[o] = fmaf(xv.w, w3[o], a);
            }
        }
        #pragma unroll
        for (int o = 0; o < 32; ++o) acc[o] = fmaxf(acc[o], 0.f);

        // layer 2 (32->32)
        float a2[32];
        #pragma unroll
        for (int o = 0; o < 32; ++o) a2[o] = h_b2[o];
        #pragma unroll 8
        for (int k = 0; k < 32; ++k) {
            const float hk = acc[k];
            const float* wr = h_w2 + k * 32;
            #pragma unroll
            for (int o = 0; o < 32; ++o) a2[o] = fmaf(hk, wr[o], a2[o]);
        }
        #pragma unroll
        for (int o = 0; o < 32; ++o) a2[o] = fmaxf(a2[o], 0.f);

        // layer 3 (32->16, linear)
        float ho[16];
        #pragma unroll
        for (int o = 0; o < 16; ++o) ho[o] = h_b3[o];
        #pragma unroll 8
        for (int k = 0; k < 32; ++k) {
            const float hk = a2[k];
            const float* wr = h_w3 + k * 16;
            #pragma unroll
            for (int o = 0; o < 16; ++o) ho[o] = fmaf(hk, wr[o], ho[o]);
        }

        // u = ho @ cW1[:16], v = ho @ cW1[16:]
        float u[16], v[16];
        #pragma unroll
        for (int o = 0; o < 16; ++o) { u[o] = 0.f; v[o] = 0.f; }
        #pragma unroll 8
        for (int k = 0; k < 16; ++k) {
            const float hk = ho[k];
            const float* wu = c_w1 + k * 16;
            const float* wv = c_w1 + (16 + k) * 16;
            #pragma unroll
            for (int o = 0; o < 16; ++o) {
                u[o] = fmaf(hk, wu[o], u[o]);
                v[o] = fmaf(hk, wv[o], v[o]);
            }
        }

        #pragma unroll
        for (int cc = 0; cc < 8; ++cc)
            ho32[tid * 9 + cc] = pack_bf(ho[2 * cc], ho[2 * cc + 1]);
        #pragma unroll
        for (int cc = 0; cc < 8; ++cc) {
            uv32[tid * 17 + cc]     = pack_bf(u[2 * cc], u[2 * cc + 1]);
            uv32[tid * 17 + 8 + cc] = pack_bf(v[2 * cc], v[2 * cc + 1]);
        }
    }
    __syncthreads();

    // ===== Phase C: 50 pairs/sample, counter L2/L3 + pool2, 10 lanes/sample =====
    if (tid < vs * 10) {
        const int s = tid / 10;
        const int t10 = tid % 10;
        const int half = t10 / 5;
        const int pg = t10 % 5;
        float pm0 = -1e30f, pm1 = -1e30f, pm2 = -1e30f, pm3 = -1e30f;
        for (int n = 0; n < 5; ++n) {
            int i, j;
            if (half == 0) { i = pg; j = 5 + n; } else { i = 5 + pg; j = n; }
            const unsigned* ur  = uv32 + (s * 10 + i) * 17;
            const unsigned* vrw = uv32 + (s * 10 + j) * 17 + 8;
            float h1p[16];
            #pragma unroll
            for (int cc = 0; cc < 8; ++cc) {
                const unsigned uu = ur[cc], vv = vrw[cc];
                h1p[2 * cc]     = fmaxf(bf_lo(uu) + bf_lo(vv) + c_b1[2 * cc], 0.f);
                h1p[2 * cc + 1] = fmaxf(bf_hi(uu) + bf_hi(vv) + c_b1[2 * cc + 1], 0.f);
            }
            float a[16];
            #pragma unroll
            for (int o = 0; o < 16; ++o) a[o] = c_b2[o];
            #pragma unroll
            for (int k = 0; k < 16; ++k) {
                const float hk = h1p[k];
                const float* wr = c_w2 + k * 16;
                #pragma unroll
                for (int o = 0; o < 16; ++o) a[o] = fmaf(hk, wr[o], a[o]);
            }
            float c3[8];
            #pragma unroll
            for (int o = 0; o < 8; ++o) c3[o] = c_b3[o];
            #pragma unroll
            for (int k = 0; k < 16; ++k) {
                const float hk = fmaxf(a[k], 0.f);
                const float* wr = c_w3 + k * 8;
                #pragma unroll
                for (int o = 0; o < 8; ++o) c3[o] = fmaf(hk, wr[o], c3[o]);
            }
            pm0 = fmaxf(pm0, fmaxf(c3[0], c3[1]));
            pm1 = fmaxf(pm1, fmaxf(c3[2], c3[3]));
            pm2 = fmaxf(pm2, fmaxf(c3[4], c3[5]));
            pm3 = fmaxf(pm3, fmaxf(c3[6], c3[7]));
        }
        float* dst = sPm + ((s * 2 + half) * 5 + pg) * 4;
        dst[0] = pm0; dst[1] = pm1; dst[2] = pm2; dst[3] = pm3;
    }
    __syncthreads();

    // ===== Phase D: max over 5 groups -> g =====
    if (tid < vs * 8) {
        const int s = tid >> 3;
        const int r = tid & 7;            // half*4 + m
        const int half = r >> 2, m = r & 3;
        float mx = -1e30f;
        #pragma unroll
        for (int pg = 0; pg < 5; ++pg)
            mx = fmaxf(mx, sPm[((s * 2 + half) * 5 + pg) * 4 + m]);
        sG[s * 8 + r] = mx;
    }
    __syncthreads();

    // ===== Phase E1: team layer 1 (84 -> 64), 4 lanes/row =====
    if (tid < vs * 8) {
        const int s = tid >> 3;
        const int half = (tid >> 2) & 1;
        const int q = tid & 3;
        const int o0 = q * 16;
        float a[16];
        #pragma unroll
        for (int o = 0; o < 16; ++o) a[o] = t_b1[o0 + o];
        for (int h5 = 0; h5 < 5; ++h5) {
            const int row = s * 10 + half * 5 + h5;
            #pragma unroll
            for (int cc = 0; cc < 8; ++cc) {
                const unsigned hv = ho32[row * 9 + cc];
                const float x0 = bf_lo(hv), x1 = bf_hi(hv);
                const int k0 = h5 * 16 + 2 * cc;
                #pragma unroll
                for (int ob = 0; ob < 4; ++ob) {
                    const float4 w0 = *(const float4*)(t_w1 + k0 * 64 + o0 + ob * 4);
                    const float4 w1 = *(const float4*)(t_w1 + (k0 + 1) * 64 + o0 + ob * 4);
                    a[ob * 4 + 0] = fmaf(x0, w0.x, a[ob * 4 + 0]);
                    a[ob * 4 + 1] = fmaf(x0, w0.y, a[ob * 4 + 1]);
                    a[ob * 4 + 2] = fmaf(x0, w0.z, a[ob * 4 + 2]);
                    a[ob * 4 + 3] = fmaf(x0, w0.w, a[ob * 4 + 3]);
                    a[ob * 4 + 0] = fmaf(x1, w1.x, a[ob * 4 + 0]);
                    a[ob * 4 + 1] = fmaf(x1, w1.y, a[ob * 4 + 1]);
                    a[ob * 4 + 2] = fmaf(x1, w1.z, a[ob * 4 + 2]);
                    a[ob * 4 + 3] = fmaf(x1, w1.w, a[ob * 4 + 3]);
                }
            }
        }
        #pragma unroll
        for (int m = 0; m < 4; ++m) {
            const float gv = sG[s * 8 + half * 4 + m];
            #pragma unroll
            for (int ob = 0; ob < 4; ++ob) {
                const float4 w = *(const float4*)(t_w1 + (80 + m) * 64 + o0 + ob * 4);
                a[ob * 4 + 0] = fmaf(gv, w.x, a[ob * 4 + 0]);
                a[ob * 4 + 1] = fmaf(gv, w.y, a[ob * 4 + 1]);
                a[ob * 4 + 2] = fmaf(gv, w.z, a[ob * 4 + 2]);
                a[ob * 4 + 3] = fmaf(gv, w.w, a[ob * 4 + 3]);
            }
        }
        const int row48 = s * 2 + half;
        #pragma unroll
        for (int cc = 0; cc < 8; ++cc)
            h1t[row48 * 33 + q * 8 + cc] =
                pack_bf(fmaxf(a[2 * cc], 0.f), fmaxf(a[2 * cc + 1], 0.f));
    }
    __syncthreads();

    // ===== Phase E2: team layer 2 (64 -> 64) =====
    if (tid < vs * 8) {
        const int s = tid >> 3;
        const int half = (tid >> 2) & 1;
        const int q = tid & 3;
        const int o0 = q * 16;
        const int row48 = s * 2 + half;
        float a[16];
        #pragma unroll
        for (int o = 0; o < 16; ++o) a[o] = t_b2[o0 + o];
        #pragma unroll 8
        for (int cc = 0; cc < 32; ++cc) {
            const unsigned hv = h1t[row48 * 33 + cc];
            const float x0 = bf_lo(hv), x1 = bf_hi(hv);
            #pragma unroll
            for (int ob = 0; ob < 4; ++ob) {
                const float4 w0 = *(const float4*)(t_w2 + (2 * cc) * 64 + o0 + ob * 4);
                const float4 w1 = *(const float4*)(t_w2 + (2 * cc + 1) * 64 + o0 + ob * 4);
                a[ob * 4 + 0] = fmaf(x0, w0.x, a[ob * 4 + 0]);
                a[ob * 4 + 1] = fmaf(x0, w0.y, a[ob * 4 + 1]);
                a[ob * 4 + 2] = fmaf(x0, w0.z, a[ob * 4 + 2]);
                a[ob * 4 + 3] = fmaf(x0, w0.w, a[ob * 4 + 3]);
                a[ob * 4 + 0] = fmaf(x1, w1.x, a[ob * 4 + 0]);
                a[ob * 4 + 1] = fmaf(x1, w1.y, a[ob * 4 + 1]);
                a[ob * 4 + 2] = fmaf(x1, w1.z, a[ob * 4 + 2]);
                a[ob * 4 + 3] = fmaf(x1, w1.w, a[ob * 4 + 3]);
            }
        }
        #pragma unroll
        for (int cc = 0; cc < 8; ++cc)
            h2t[row48 * 33 + q * 8 + cc] =
                pack_bf(fmaxf(a[2 * cc], 0.f), fmaxf(a[2 * cc + 1], 0.f));
    }
    __syncthreads();

    // ===== Phase E3: team layer 3 (64 -> 16, linear) =====
    if (tid < vs * 8) {
        const int s = tid >> 3;
        const int half = (tid >> 2) & 1;
        const int q = tid & 3;
        const int o0 = q * 4;
        const int row48 = s * 2 + half;
        float a0 = t_b3[o0], a1 = t_b3[o0 + 1], a2 = t_b3[o0 + 2], a3 = t_b3[o0 + 3];
        #pragma unroll 8
        for (int cc = 0; cc < 32; ++cc) {
            const unsigned hv = h2t[row48 * 33 + cc];
            const float x0 = bf_lo(hv), x1 = bf_hi(hv);
            const float4 w0 = *(const float4*)(t_w3 + (2 * cc) * 16 + o0);
            const float4 w1 = *(const float4*)(t_w3 + (2 * cc + 1) * 16 + o0);
            a0 = fmaf(x0, w0.x, a0); a1 = fmaf(x0, w0.y, a1);
            a2 = fmaf(x0, w0.z, a2); a3 = fmaf(x0, w0.w, a3);
            a0 = fmaf(x1, w1.x, a0); a1 = fmaf(x1, w1.y, a1);
            a2 = fmaf(x1, w1.z, a2); a3 = fmaf(x1, w1.w, a3);
        }
        float* dst = sT + s * 33 + half * 16 + o0;
        dst[0] = a0; dst[1] = a1; dst[2] = a2; dst[3] = a3;
    }
    __syncthreads();

    // ===== Phase F: final MLP (32->16->16->2) + softmax, 1 lane/sample =====
    if (tid < vs) {
        const float* tr = sT + tid * 33;
        float g1[16];
        #pragma unroll
        for (int o = 0; o < 16; ++o) g1[o] = f_b1[o];
        #pragma unroll 8
        for (int k = 0; k < 32; ++k) {
            const float hk = tr[k];
            const float* wr = f_w1 + k * 16;
            #pragma unroll
            for (int o = 0; o < 16; ++o) g1[o] = fmaf(hk, wr[o], g1[o]);
        }
        float g2[16];
        #pragma unroll
        for (int o = 0; o < 16; ++o) g2[o] = f_b2[o];
        #pragma unroll 8
        for (int k = 0; k < 16; ++k) {
            const float hk = fmaxf(g1[k], 0.f);
            const float* wr = f_w2 + k * 16;
            #pragma unroll
            for (int o = 0; o < 16; ++o) g2[o] = fmaf(hk, wr[o], g2[o]);
        }
        float l0 = f_b3[0], l1 = f_b3[1];
        #pragma unroll
        for (int k = 0; k < 16; ++k) {
            const float hk = fmaxf(g2[k], 0.f);
            l0 = fmaf(hk, f_w3[2 * k], l0);
            l1 = fmaf(hk, f_w3[2 * k + 1], l1);
        }
        const float e = expf(l1 - l0);
        const float p0 = 1.f / (1.f + e);
        out[(size_t)(s0 + tid) * 2]     = p0;
        out[(size_t)(s0 + tid) * 2 + 1] = 1.f - p0;
    }
}

extern "C" void kernel_launch(void* const* d_in, const int* in_sizes, int n_in,
                              void* d_out, int out_size, void* d_ws, size_t ws_size,
                              hipStream_t stream) {
    (void)in_sizes; (void)n_in; (void)d_ws; (void)ws_size; (void)out_size;
    const float* x    = (const float*)d_in[0];
    const float* h_w1 = (const float*)d_in[1];  const float* h_b1 = (const float*)d_in[2];
    const float* h_w2 = (const float*)d_in[3];  const float* h_b2 = (const float*)d_in[4];
    const float* h_w3 = (const float*)d_in[5];  const float* h_b3 = (const float*)d_in[6];
    const float* c_w1 = (const float*)d_in[7];  const float* c_b1 = (const float*)d_in[8];
    const float* c_w2 = (const float*)d_in[9];  const float* c_b2 = (const float*)d_in[10];
    const float* c_w3 = (const float*)d_in[11]; const float* c_b3 = (const float*)d_in[12];
    const float* t_w1 = (const float*)d_in[13]; const float* t_b1 = (const float*)d_in[14];
    const float* t_w2 = (const float*)d_in[15]; const float* t_b2 = (const float*)d_in[16];
    const float* t_w3 = (const float*)d_in[17]; const float* t_b3 = (const float*)d_in[18];
    const float* f_w1 = (const float*)d_in[19]; const float* f_b1 = (const float*)d_in[20];
    const float* f_w2 = (const float*)d_in[21]; const float* f_b2 = (const float*)d_in[22];
    const float* f_w3 = (const float*)d_in[23]; const float* f_b3 = (const float*)d_in[24];
    float* out = (float*)d_out;

    const int grid = (NB + SPB - 1) / SPB;   // 2622 workgroups
    fused_model_kernel<<<grid, THREADS, 0, stream>>>(
        x, h_w1, h_b1, h_w2, h_b2, h_w3, h_b3,
        c_w1, c_b1, c_w2, c_b2, c_w3, c_b3,
        t_w1, t_b1, t_w2, t_b2, t_w3, t_b3,
        f_w1, f_b1, f_w2, f_b2, f_w3, f_b3,
        out);
}

// Round 6
// 495.093 us; speedup vs baseline: 2.9247x; 1.1296x over previous
//
#include <hip/hip_runtime.h>
#include <hip/hip_bf16.h>
#include <math.h>

// Round 6: round-5 structure, spill fixed.
//  Round-5 diagnosis: __launch_bounds__(256,5) squeezed VGPR to 48 ->
//  acc[32]/a2[32] spilled to scratch (WRITE_SIZE 410MB). Single change:
//  bound (256,4) -> VGPR cap 128 (peak live ~85), no spill, 4 wg/CU.

#define THREADS 256
#define SPB 25
#define NB 65536

__device__ __forceinline__ unsigned bfr(float f) {
    unsigned u = __float_as_uint(f);
    return (u + 0x7fffu + ((u >> 16) & 1u)) >> 16;   // RNE to bf16
}
__device__ __forceinline__ unsigned pack_bf(float a, float b) {
    return bfr(a) | (bfr(b) << 16);
}
__device__ __forceinline__ float bf_lo(unsigned u) { return __uint_as_float(u << 16); }
__device__ __forceinline__ float bf_hi(unsigned u) { return __uint_as_float(u & 0xffff0000u); }

__global__ __launch_bounds__(THREADS, 4) void fused_model_kernel(
    const float* __restrict__ x,
    const float* __restrict__ h_w1, const float* __restrict__ h_b1,
    const float* __restrict__ h_w2, const float* __restrict__ h_b2,
    const float* __restrict__ h_w3, const float* __restrict__ h_b3,
    const float* __restrict__ c_w1, const float* __restrict__ c_b1,
    const float* __restrict__ c_w2, const float* __restrict__ c_b2,
    const float* __restrict__ c_w3, const float* __restrict__ c_b3,
    const float* __restrict__ t_w1, const float* __restrict__ t_b1,
    const float* __restrict__ t_w2, const float* __restrict__ t_b2,
    const float* __restrict__ t_w3, const float* __restrict__ t_b3,
    const float* __restrict__ f_w1, const float* __restrict__ f_b1,
    const float* __restrict__ f_w2, const float* __restrict__ f_b2,
    const float* __restrict__ f_w3, const float* __restrict__ f_b3,
    float* __restrict__ out)
{
    // LDS arena: 7700 u32 = 30800 B.
    //  [0,2250)     ho32 u32 bf16x2, 250 rows x 9   (A..E1)
    //  [2250,6500)  uv32 u32 bf16x2, 250 rows x 17  (A..C)
    //     alias: h1t [2250,3900) 50x33 (E1..E2), h2t [3900,5550) (E2..E3)
    //  [6500,7500)  sPm  f32 25*2*5*4 (C..D);  alias sT f32 25x33 (E3..F)
    //  [7500,7700)  sG   f32 25x8 (D..E1)
    __shared__ unsigned smem_u[7700];
    unsigned* const ho32 = smem_u;
    unsigned* const uv32 = smem_u + 2250;
    unsigned* const h1t  = smem_u + 2250;
    unsigned* const h2t  = smem_u + 3900;
    float*    const sPm  = (float*)(smem_u + 6500);
    float*    const sT   = (float*)(smem_u + 6500);
    float*    const sG   = (float*)(smem_u + 7500);

    const int tid = threadIdx.x;
    const int wg  = blockIdx.x;
    const int s0  = wg * SPB;
    const int vs  = (NB - s0 < SPB) ? (NB - s0) : SPB;
    const int vr  = vs * 10;

    // ===== Phase A: hero chain + u/v, one row per lane, weights in SGPRs =====
    if (tid < vr) {
        const float* xr = x + ((size_t)s0 * 10 + tid) * 140;
        float acc[32];
        #pragma unroll
        for (int o = 0; o < 32; ++o) acc[o] = h_b1[o];
        #pragma unroll 5
        for (int q = 0; q < 35; ++q) {
            const float4 xv = *(const float4*)(xr + q * 4);
            const float* w0 = h_w1 + (q * 4 + 0) * 32;
            const float* w1 = h_w1 + (q * 4 + 1) * 32;
            const float* w2 = h_w1 + (q * 4 + 2) * 32;
            const float* w3 = h_w1 + (q * 4 + 3) * 32;
            #pragma unroll
            for (int o = 0; o < 32; ++o) {
                float a = fmaf(xv.x, w0[o], acc[o]);
                a = fmaf(xv.y, w1[o], a);
                a = fmaf(xv.z, w2[o], a);
                acc[o] = fmaf(xv.w, w3[o], a);
            }
        }
        #pragma unroll
        for (int o = 0; o < 32; ++o) acc[o] = fmaxf(acc[o], 0.f);

        // layer 2 (32->32)
        float a2[32];
        #pragma unroll
        for (int o = 0; o < 32; ++o) a2[o] = h_b2[o];
        #pragma unroll 8
        for (int k = 0; k < 32; ++k) {
            const float hk = acc[k];
            const float* wr = h_w2 + k * 32;
            #pragma unroll
            for (int o = 0; o < 32; ++o) a2[o] = fmaf(hk, wr[o], a2[o]);
        }
        #pragma unroll
        for (int o = 0; o < 32; ++o) a2[o] = fmaxf(a2[o], 0.f);

        // layer 3 (32->16, linear)
        float ho[16];
        #pragma unroll
        for (int o = 0; o < 16; ++o) ho[o] = h_b3[o];
        #pragma unroll 8
        for (int k = 0; k < 32; ++k) {
            const float hk = a2[k];
            const float* wr = h_w3 + k * 16;
            #pragma unroll
            for (int o = 0; o < 16; ++o) ho[o] = fmaf(hk, wr[o], ho[o]);
        }

        // u = ho @ cW1[:16], v = ho @ cW1[16:]
        float u[16], v[16];
        #pragma unroll
        for (int o = 0; o < 16; ++o) { u[o] = 0.f; v[o] = 0.f; }
        #pragma unroll 8
        for (int k = 0; k < 16; ++k) {
            const float hk = ho[k];
            const float* wu = c_w1 + k * 16;
            const float* wv = c_w1 + (16 + k) * 16;
            #pragma unroll
            for (int o = 0; o < 16; ++o) {
                u[o] = fmaf(hk, wu[o], u[o]);
                v[o] = fmaf(hk, wv[o], v[o]);
            }
        }

        #pragma unroll
        for (int cc = 0; cc < 8; ++cc)
            ho32[tid * 9 + cc] = pack_bf(ho[2 * cc], ho[2 * cc + 1]);
        #pragma unroll
        for (int cc = 0; cc < 8; ++cc) {
            uv32[tid * 17 + cc]     = pack_bf(u[2 * cc], u[2 * cc + 1]);
            uv32[tid * 17 + 8 + cc] = pack_bf(v[2 * cc], v[2 * cc + 1]);
        }
    }
    __syncthreads();

    // ===== Phase C: 50 pairs/sample, counter L2/L3 + pool2, 10 lanes/sample =====
    if (tid < vs * 10) {
        const int s = tid / 10;
        const int t10 = tid % 10;
        const int half = t10 / 5;
        const int pg = t10 % 5;
        float pm0 = -1e30f, pm1 = -1e30f, pm2 = -1e30f, pm3 = -1e30f;
        for (int n = 0; n < 5; ++n) {
            int i, j;
            if (half == 0) { i = pg; j = 5 + n; } else { i = 5 + pg; j = n; }
            const unsigned* ur  = uv32 + (s * 10 + i) * 17;
            const unsigned* vrw = uv32 + (s * 10 + j) * 17 + 8;
            float h1p[16];
            #pragma unroll
            for (int cc = 0; cc < 8; ++cc) {
                const unsigned uu = ur[cc], vv = vrw[cc];
                h1p[2 * cc]     = fmaxf(bf_lo(uu) + bf_lo(vv) + c_b1[2 * cc], 0.f);
                h1p[2 * cc + 1] = fmaxf(bf_hi(uu) + bf_hi(vv) + c_b1[2 * cc + 1], 0.f);
            }
            float a[16];
            #pragma unroll
            for (int o = 0; o < 16; ++o) a[o] = c_b2[o];
            #pragma unroll
            for (int k = 0; k < 16; ++k) {
                const float hk = h1p[k];
                const float* wr = c_w2 + k * 16;
                #pragma unroll
                for (int o = 0; o < 16; ++o) a[o] = fmaf(hk, wr[o], a[o]);
            }
            float c3[8];
            #pragma unroll
            for (int o = 0; o < 8; ++o) c3[o] = c_b3[o];
            #pragma unroll
            for (int k = 0; k < 16; ++k) {
                const float hk = fmaxf(a[k], 0.f);
                const float* wr = c_w3 + k * 8;
                #pragma unroll
                for (int o = 0; o < 8; ++o) c3[o] = fmaf(hk, wr[o], c3[o]);
            }
            pm0 = fmaxf(pm0, fmaxf(c3[0], c3[1]));
            pm1 = fmaxf(pm1, fmaxf(c3[2], c3[3]));
            pm2 = fmaxf(pm2, fmaxf(c3[4], c3[5]));
            pm3 = fmaxf(pm3, fmaxf(c3[6], c3[7]));
        }
        float* dst = sPm + ((s * 2 + half) * 5 + pg) * 4;
        dst[0] = pm0; dst[1] = pm1; dst[2] = pm2; dst[3] = pm3;
    }
    __syncthreads();

    // ===== Phase D: max over 5 groups -> g =====
    if (tid < vs * 8) {
        const int s = tid >> 3;
        const int r = tid & 7;            // half*4 + m
        const int half = r >> 2, m = r & 3;
        float mx = -1e30f;
        #pragma unroll
        for (int pg = 0; pg < 5; ++pg)
            mx = fmaxf(mx, sPm[((s * 2 + half) * 5 + pg) * 4 + m]);
        sG[s * 8 + r] = mx;
    }
    __syncthreads();

    // ===== Phase E1: team layer 1 (84 -> 64), 4 lanes/row =====
    if (tid < vs * 8) {
        const int s = tid >> 3;
        const int half = (tid >> 2) & 1;
        const int q = tid & 3;
        const int o0 = q * 16;
        float a[16];
        #pragma unroll
        for (int o = 0; o < 16; ++o) a[o] = t_b1[o0 + o];
        for (int h5 = 0; h5 < 5; ++h5) {
            const int row = s * 10 + half * 5 + h5;
            #pragma unroll
            for (int cc = 0; cc < 8; ++cc) {
                const unsigned hv = ho32[row * 9 + cc];
                const float x0 = bf_lo(hv), x1 = bf_hi(hv);
                const int k0 = h5 * 16 + 2 * cc;
                #pragma unroll
                for (int ob = 0; ob < 4; ++ob) {
                    const float4 w0 = *(const float4*)(t_w1 + k0 * 64 + o0 + ob * 4);
                    const float4 w1 = *(const float4*)(t_w1 + (k0 + 1) * 64 + o0 + ob * 4);
                    a[ob * 4 + 0] = fmaf(x0, w0.x, a[ob * 4 + 0]);
                    a[ob * 4 + 1] = fmaf(x0, w0.y, a[ob * 4 + 1]);
                    a[ob * 4 + 2] = fmaf(x0, w0.z, a[ob * 4 + 2]);
                    a[ob * 4 + 3] = fmaf(x0, w0.w, a[ob * 4 + 3]);
                    a[ob * 4 + 0] = fmaf(x1, w1.x, a[ob * 4 + 0]);
                    a[ob * 4 + 1] = fmaf(x1, w1.y, a[ob * 4 + 1]);
                    a[ob * 4 + 2] = fmaf(x1, w1.z, a[ob * 4 + 2]);
                    a[ob * 4 + 3] = fmaf(x1, w1.w, a[ob * 4 + 3]);
                }
            }
        }
        #pragma unroll
        for (int m = 0; m < 4; ++m) {
            const float gv = sG[s * 8 + half * 4 + m];
            #pragma unroll
            for (int ob = 0; ob < 4; ++ob) {
                const float4 w = *(const float4*)(t_w1 + (80 + m) * 64 + o0 + ob * 4);
                a[ob * 4 + 0] = fmaf(gv, w.x, a[ob * 4 + 0]);
                a[ob * 4 + 1] = fmaf(gv, w.y, a[ob * 4 + 1]);
                a[ob * 4 + 2] = fmaf(gv, w.z, a[ob * 4 + 2]);
                a[ob * 4 + 3] = fmaf(gv, w.w, a[ob * 4 + 3]);
            }
        }
        const int row48 = s * 2 + half;
        #pragma unroll
        for (int cc = 0; cc < 8; ++cc)
            h1t[row48 * 33 + q * 8 + cc] =
                pack_bf(fmaxf(a[2 * cc], 0.f), fmaxf(a[2 * cc + 1], 0.f));
    }
    __syncthreads();

    // ===== Phase E2: team layer 2 (64 -> 64) =====
    if (tid < vs * 8) {
        const int s = tid >> 3;
        const int half = (tid >> 2) & 1;
        const int q = tid & 3;
        const int o0 = q * 16;
        const int row48 = s * 2 + half;
        float a[16];
        #pragma unroll
        for (int o = 0; o < 16; ++o) a[o] = t_b2[o0 + o];
        #pragma unroll 8
        for (int cc = 0; cc < 32; ++cc) {
            const unsigned hv = h1t[row48 * 33 + cc];
            const float x0 = bf_lo(hv), x1 = bf_hi(hv);
            #pragma unroll
            for (int ob = 0; ob < 4; ++ob) {
                const float4 w0 = *(const float4*)(t_w2 + (2 * cc) * 64 + o0 + ob * 4);
                const float4 w1 = *(const float4*)(t_w2 + (2 * cc + 1) * 64 + o0 + ob * 4);
                a[ob * 4 + 0] = fmaf(x0, w0.x, a[ob * 4 + 0]);
                a[ob * 4 + 1] = fmaf(x0, w0.y, a[ob * 4 + 1]);
                a[ob * 4 + 2] = fmaf(x0, w0.z, a[ob * 4 + 2]);
                a[ob * 4 + 3] = fmaf(x0, w0.w, a[ob * 4 + 3]);
                a[ob * 4 + 0] = fmaf(x1, w1.x, a[ob * 4 + 0]);
                a[ob * 4 + 1] = fmaf(x1, w1.y, a[ob * 4 + 1]);
                a[ob * 4 + 2] = fmaf(x1, w1.z, a[ob * 4 + 2]);
                a[ob * 4 + 3] = fmaf(x1, w1.w, a[ob * 4 + 3]);
            }
        }
        #pragma unroll
        for (int cc = 0; cc < 8; ++cc)
            h2t[row48 * 33 + q * 8 + cc] =
                pack_bf(fmaxf(a[2 * cc], 0.f), fmaxf(a[2 * cc + 1], 0.f));
    }
    __syncthreads();

    // ===== Phase E3: team layer 3 (64 -> 16, linear) =====
    if (tid < vs * 8) {
        const int s = tid >> 3;
        const int half = (tid >> 2) & 1;
        const int q = tid & 3;
        const int o0 = q * 4;
        const int row48 = s * 2 + half;
        float a0 = t_b3[o0], a1 = t_b3[o0 + 1], a2 = t_b3[o0 + 2], a3 = t_b3[o0 + 3];
        #pragma unroll 8
        for (int cc = 0; cc < 32; ++cc) {
            const unsigned hv = h2t[row48 * 33 + cc];
            const float x0 = bf_lo(hv), x1 = bf_hi(hv);
            const float4 w0 = *(const float4*)(t_w3 + (2 * cc) * 16 + o0);
            const float4 w1 = *(const float4*)(t_w3 + (2 * cc + 1) * 16 + o0);
            a0 = fmaf(x0, w0.x, a0); a1 = fmaf(x0, w0.y, a1);
            a2 = fmaf(x0, w0.z, a2); a3 = fmaf(x0, w0.w, a3);
            a0 = fmaf(x1, w1.x, a0); a1 = fmaf(x1, w1.y, a1);
            a2 = fmaf(x1, w1.z, a2); a3 = fmaf(x1, w1.w, a3);
        }
        float* dst = sT + s * 33 + half * 16 + o0;
        dst[0] = a0; dst[1] = a1; dst[2] = a2; dst[3] = a3;
    }
    __syncthreads();

    // ===== Phase F: final MLP (32->16->16->2) + softmax, 1 lane/sample =====
    if (tid < vs) {
        const float* tr = sT + tid * 33;
        float g1[16];
        #pragma unroll
        for (int o = 0; o < 16; ++o) g1[o] = f_b1[o];
        #pragma unroll 8
        for (int k = 0; k < 32; ++k) {
            const float hk = tr[k];
            const float* wr = f_w1 + k * 16;
            #pragma unroll
            for (int o = 0; o < 16; ++o) g1[o] = fmaf(hk, wr[o], g1[o]);
        }
        float g2[16];
        #pragma unroll
        for (int o = 0; o < 16; ++o) g2[o] = f_b2[o];
        #pragma unroll 8
        for (int k = 0; k < 16; ++k) {
            const float hk = fmaxf(g1[k], 0.f);
            const float* wr = f_w2 + k * 16;
            #pragma unroll
            for (int o = 0; o < 16; ++o) g2[o] = fmaf(hk, wr[o], g2[o]);
        }
        float l0 = f_b3[0], l1 = f_b3[1];
        #pragma unroll
        for (int k = 0; k < 16; ++k) {
            const float hk = fmaxf(g2[k], 0.f);
            l0 = fmaf(hk, f_w3[2 * k], l0);
            l1 = fmaf(hk, f_w3[2 * k + 1], l1);
        }
        const float e = expf(l1 - l0);
        const float p0 = 1.f / (1.f + e);
        out[(size_t)(s0 + tid) * 2]     = p0;
        out[(size_t)(s0 + tid) * 2 + 1] = 1.f - p0;
    }
}

extern "C" void kernel_launch(void* const* d_in, const int* in_sizes, int n_in,
                              void* d_out, int out_size, void* d_ws, size_t ws_size,
                              hipStream_t stream) {
    (void)in_sizes; (void)n_in; (void)d_ws; (void)ws_size; (void)out_size;
    const float* x    = (const float*)d_in[0];
    const float* h_w1 = (const float*)d_in[1];  const float* h_b1 = (const float*)d_in[2];
    const float* h_w2 = (const float*)d_in[3];  const float* h_b2 = (const float*)d_in[4];
    const float* h_w3 = (const float*)d_in[5];  const float* h_b3 = (const float*)d_in[6];
    const float* c_w1 = (const float*)d_in[7];  const float* c_b1 = (const float*)d_in[8];
    const float* c_w2 = (const float*)d_in[9];  const float* c_b2 = (const float*)d_in[10];
    const float* c_w3 = (const float*)d_in[11]; const float* c_b3 = (const float*)d_in[12];
    const float* t_w1 = (const float*)d_in[13]; const float* t_b1 = (const float*)d_in[14];
    const float* t_w2 = (const float*)d_in[15]; const float* t_b2 = (const float*)d_in[16];
    const float* t_w3 = (const float*)d_in[17]; const float* t_b3 = (const float*)d_in[18];
    const float* f_w1 = (const float*)d_in[19]; const float* f_b1 = (const float*)d_in[20];
    const float* f_w2 = (const float*)d_in[21]; const float* f_b2 = (const float*)d_in[22];
    const float* f_w3 = (const float*)d_in[23]; const float* f_b3 = (const float*)d_in[24];
    float* out = (float*)d_out;

    const int grid = (NB + SPB - 1) / SPB;   // 2622 workgroups
    fused_model_kernel<<<grid, THREADS, 0, stream>>>(
        x, h_w1, h_b1, h_w2, h_b2, h_w3, h_b3,
        c_w1, c_b1, c_w2, c_b2, c_w3, c_b3,
        t_w1, t_b1, t_w2, t_b2, t_w3, t_b3,
        f_w1, f_b1, f_w2, f_b2, f_w3, f_b3,
        out);
}

// Round 7
// 484.885 us; speedup vs baseline: 2.9862x; 1.0211x over previous
//
#include <hip/hip_runtime.h>
#include <hip/hip_bf16.h>
#include <math.h>

// Round 7: kill the scratch for real.
//  Rounds 5/6 diagnosis refined: WRITE_SIZE 410/192MB with VGPR=48/60 was NOT
//  budget starvation -- partial unrolls (#pragma unroll 8) left k runtime,
//  making acc[k]/a2[k]/ho[k]/g1[k] runtime-indexed register arrays -> the
//  compiler allocates them in SCRATCH (rule: runtime-indexed arrays can't
//  live in registers). Round 4 (full unrolls) had WRITE_SIZE 4.6KB.
//  Single change vs round 6: full unroll on every loop that reads a register
//  array by its index. LDS-indexed loops keep partial unrolls.

#define THREADS 256
#define SPB 25
#define NB 65536

__device__ __forceinline__ unsigned bfr(float f) {
    unsigned u = __float_as_uint(f);
    return (u + 0x7fffu + ((u >> 16) & 1u)) >> 16;   // RNE to bf16
}
__device__ __forceinline__ unsigned pack_bf(float a, float b) {
    return bfr(a) | (bfr(b) << 16);
}
__device__ __forceinline__ float bf_lo(unsigned u) { return __uint_as_float(u << 16); }
__device__ __forceinline__ float bf_hi(unsigned u) { return __uint_as_float(u & 0xffff0000u); }

__global__ __launch_bounds__(THREADS, 4) void fused_model_kernel(
    const float* __restrict__ x,
    const float* __restrict__ h_w1, const float* __restrict__ h_b1,
    const float* __restrict__ h_w2, const float* __restrict__ h_b2,
    const float* __restrict__ h_w3, const float* __restrict__ h_b3,
    const float* __restrict__ c_w1, const float* __restrict__ c_b1,
    const float* __restrict__ c_w2, const float* __restrict__ c_b2,
    const float* __restrict__ c_w3, const float* __restrict__ c_b3,
    const float* __restrict__ t_w1, const float* __restrict__ t_b1,
    const float* __restrict__ t_w2, const float* __restrict__ t_b2,
    const float* __restrict__ t_w3, const float* __restrict__ t_b3,
    const float* __restrict__ f_w1, const float* __restrict__ f_b1,
    const float* __restrict__ f_w2, const float* __restrict__ f_b2,
    const float* __restrict__ f_w3, const float* __restrict__ f_b3,
    float* __restrict__ out)
{
    // LDS arena: 7700 u32 = 30800 B.
    //  [0,2250)     ho32 u32 bf16x2, 250 rows x 9   (A..E1)
    //  [2250,6500)  uv32 u32 bf16x2, 250 rows x 17  (A..C)
    //     alias: h1t [2250,3900) 50x33 (E1..E2), h2t [3900,5550) (E2..E3)
    //  [6500,7500)  sPm  f32 25*2*5*4 (C..D);  alias sT f32 25x33 (E3..F)
    //  [7500,7700)  sG   f32 25x8 (D..E1)
    __shared__ unsigned smem_u[7700];
    unsigned* const ho32 = smem_u;
    unsigned* const uv32 = smem_u + 2250;
    unsigned* const h1t  = smem_u + 2250;
    unsigned* const h2t  = smem_u + 3900;
    float*    const sPm  = (float*)(smem_u + 6500);
    float*    const sT   = (float*)(smem_u + 6500);
    float*    const sG   = (float*)(smem_u + 7500);

    const int tid = threadIdx.x;
    const int wg  = blockIdx.x;
    const int s0  = wg * SPB;
    const int vs  = (NB - s0 < SPB) ? (NB - s0) : SPB;
    const int vr  = vs * 10;

    // ===== Phase A: hero chain + u/v, one row per lane, weights in SGPRs =====
    if (tid < vr) {
        const float* xr = x + ((size_t)s0 * 10 + tid) * 140;
        float acc[32];
        #pragma unroll
        for (int o = 0; o < 32; ++o) acc[o] = h_b1[o];
        #pragma unroll 5
        for (int q = 0; q < 35; ++q) {      // acc indexed only by static o: ok partial
            const float4 xv = *(const float4*)(xr + q * 4);
            const float* w0 = h_w1 + (q * 4 + 0) * 32;
            const float* w1 = h_w1 + (q * 4 + 1) * 32;
            const float* w2 = h_w1 + (q * 4 + 2) * 32;
            const float* w3 = h_w1 + (q * 4 + 3) * 32;
            #pragma unroll
            for (int o = 0; o < 32; ++o) {
                float a = fmaf(xv.x, w0[o], acc[o]);
                a = fmaf(xv.y, w1[o], a);
                a = fmaf(xv.z, w2[o], a);
                acc[o] = fmaf(xv.w, w3[o], a);
            }
        }
        #pragma unroll
        for (int o = 0; o < 32; ++o) acc[o] = fmaxf(acc[o], 0.f);

        // layer 2 (32->32) -- FULL unroll: acc[k] must stay static-indexed
        float a2[32];
        #pragma unroll
        for (int o = 0; o < 32; ++o) a2[o] = h_b2[o];
        #pragma unroll
        for (int k = 0; k < 32; ++k) {
            const float hk = acc[k];
            const float* wr = h_w2 + k * 32;
            #pragma unroll
            for (int o = 0; o < 32; ++o) a2[o] = fmaf(hk, wr[o], a2[o]);
        }
        #pragma unroll
        for (int o = 0; o < 32; ++o) a2[o] = fmaxf(a2[o], 0.f);

        // layer 3 (32->16, linear) -- FULL unroll (a2[k])
        float ho[16];
        #pragma unroll
        for (int o = 0; o < 16; ++o) ho[o] = h_b3[o];
        #pragma unroll
        for (int k = 0; k < 32; ++k) {
            const float hk = a2[k];
            const float* wr = h_w3 + k * 16;
            #pragma unroll
            for (int o = 0; o < 16; ++o) ho[o] = fmaf(hk, wr[o], ho[o]);
        }

        // u = ho @ cW1[:16], v = ho @ cW1[16:] -- FULL unroll (ho[k])
        float u[16], v[16];
        #pragma unroll
        for (int o = 0; o < 16; ++o) { u[o] = 0.f; v[o] = 0.f; }
        #pragma unroll
        for (int k = 0; k < 16; ++k) {
            const float hk = ho[k];
            const float* wu = c_w1 + k * 16;
            const float* wv = c_w1 + (16 + k) * 16;
            #pragma unroll
            for (int o = 0; o < 16; ++o) {
                u[o] = fmaf(hk, wu[o], u[o]);
                v[o] = fmaf(hk, wv[o], v[o]);
            }
        }

        #pragma unroll
        for (int cc = 0; cc < 8; ++cc)
            ho32[tid * 9 + cc] = pack_bf(ho[2 * cc], ho[2 * cc + 1]);
        #pragma unroll
        for (int cc = 0; cc < 8; ++cc) {
            uv32[tid * 17 + cc]     = pack_bf(u[2 * cc], u[2 * cc + 1]);
            uv32[tid * 17 + 8 + cc] = pack_bf(v[2 * cc], v[2 * cc + 1]);
        }
    }
    __syncthreads();

    // ===== Phase C: 50 pairs/sample, counter L2/L3 + pool2, 10 lanes/sample =====
    if (tid < vs * 10) {
        const int s = tid / 10;
        const int t10 = tid % 10;
        const int half = t10 / 5;
        const int pg = t10 % 5;
        float pm0 = -1e30f, pm1 = -1e30f, pm2 = -1e30f, pm3 = -1e30f;
        for (int n = 0; n < 5; ++n) {
            int i, j;
            if (half == 0) { i = pg; j = 5 + n; } else { i = 5 + pg; j = n; }
            const unsigned* ur  = uv32 + (s * 10 + i) * 17;
            const unsigned* vrw = uv32 + (s * 10 + j) * 17 + 8;
            float h1p[16];
            #pragma unroll
            for (int cc = 0; cc < 8; ++cc) {
                const unsigned uu = ur[cc], vv = vrw[cc];
                h1p[2 * cc]     = fmaxf(bf_lo(uu) + bf_lo(vv) + c_b1[2 * cc], 0.f);
                h1p[2 * cc + 1] = fmaxf(bf_hi(uu) + bf_hi(vv) + c_b1[2 * cc + 1], 0.f);
            }
            float a[16];
            #pragma unroll
            for (int o = 0; o < 16; ++o) a[o] = c_b2[o];
            #pragma unroll
            for (int k = 0; k < 16; ++k) {
                const float hk = h1p[k];
                const float* wr = c_w2 + k * 16;
                #pragma unroll
                for (int o = 0; o < 16; ++o) a[o] = fmaf(hk, wr[o], a[o]);
            }
            float c3[8];
            #pragma unroll
            for (int o = 0; o < 8; ++o) c3[o] = c_b3[o];
            #pragma unroll
            for (int k = 0; k < 16; ++k) {
                const float hk = fmaxf(a[k], 0.f);
                const float* wr = c_w3 + k * 8;
                #pragma unroll
                for (int o = 0; o < 8; ++o) c3[o] = fmaf(hk, wr[o], c3[o]);
            }
            pm0 = fmaxf(pm0, fmaxf(c3[0], c3[1]));
            pm1 = fmaxf(pm1, fmaxf(c3[2], c3[3]));
            pm2 = fmaxf(pm2, fmaxf(c3[4], c3[5]));
            pm3 = fmaxf(pm3, fmaxf(c3[6], c3[7]));
        }
        float* dst = sPm + ((s * 2 + half) * 5 + pg) * 4;
        dst[0] = pm0; dst[1] = pm1; dst[2] = pm2; dst[3] = pm3;
    }
    __syncthreads();

    // ===== Phase D: max over 5 groups -> g =====
    if (tid < vs * 8) {
        const int s = tid >> 3;
        const int r = tid & 7;            // half*4 + m
        const int half = r >> 2, m = r & 3;
        float mx = -1e30f;
        #pragma unroll
        for (int pg = 0; pg < 5; ++pg)
            mx = fmaxf(mx, sPm[((s * 2 + half) * 5 + pg) * 4 + m]);
        sG[s * 8 + r] = mx;
    }
    __syncthreads();

    // ===== Phase E1: team layer 1 (84 -> 64), 4 lanes/row =====
    if (tid < vs * 8) {
        const int s = tid >> 3;
        const int half = (tid >> 2) & 1;
        const int q = tid & 3;
        const int o0 = q * 16;
        float a[16];
        #pragma unroll
        for (int o = 0; o < 16; ++o) a[o] = t_b1[o0 + o];
        for (int h5 = 0; h5 < 5; ++h5) {
            const int row = s * 10 + half * 5 + h5;
            #pragma unroll
            for (int cc = 0; cc < 8; ++cc) {
                const unsigned hv = ho32[row * 9 + cc];
                const float x0 = bf_lo(hv), x1 = bf_hi(hv);
                const int k0 = h5 * 16 + 2 * cc;
                #pragma unroll
                for (int ob = 0; ob < 4; ++ob) {
                    const float4 w0 = *(const float4*)(t_w1 + k0 * 64 + o0 + ob * 4);
                    const float4 w1 = *(const float4*)(t_w1 + (k0 + 1) * 64 + o0 + ob * 4);
                    a[ob * 4 + 0] = fmaf(x0, w0.x, a[ob * 4 + 0]);
                    a[ob * 4 + 1] = fmaf(x0, w0.y, a[ob * 4 + 1]);
                    a[ob * 4 + 2] = fmaf(x0, w0.z, a[ob * 4 + 2]);
                    a[ob * 4 + 3] = fmaf(x0, w0.w, a[ob * 4 + 3]);
                    a[ob * 4 + 0] = fmaf(x1, w1.x, a[ob * 4 + 0]);
                    a[ob * 4 + 1] = fmaf(x1, w1.y, a[ob * 4 + 1]);
                    a[ob * 4 + 2] = fmaf(x1, w1.z, a[ob * 4 + 2]);
                    a[ob * 4 + 3] = fmaf(x1, w1.w, a[ob * 4 + 3]);
                }
            }
        }
        #pragma unroll
        for (int m = 0; m < 4; ++m) {
            const float gv = sG[s * 8 + half * 4 + m];
            #pragma unroll
            for (int ob = 0; ob < 4; ++ob) {
                const float4 w = *(const float4*)(t_w1 + (80 + m) * 64 + o0 + ob * 4);
                a[ob * 4 + 0] = fmaf(gv, w.x, a[ob * 4 + 0]);
                a[ob * 4 + 1] = fmaf(gv, w.y, a[ob * 4 + 1]);
                a[ob * 4 + 2] = fmaf(gv, w.z, a[ob * 4 + 2]);
                a[ob * 4 + 3] = fmaf(gv, w.w, a[ob * 4 + 3]);
            }
        }
        const int row48 = s * 2 + half;
        #pragma unroll
        for (int cc = 0; cc < 8; ++cc)
            h1t[row48 * 33 + q * 8 + cc] =
                pack_bf(fmaxf(a[2 * cc], 0.f), fmaxf(a[2 * cc + 1], 0.f));
    }
    __syncthreads();

    // ===== Phase E2: team layer 2 (64 -> 64) =====
    if (tid < vs * 8) {
        const int s = tid >> 3;
        const int half = (tid >> 2) & 1;
        const int q = tid & 3;
        const int o0 = q * 16;
        const int row48 = s * 2 + half;
        float a[16];
        #pragma unroll
        for (int o = 0; o < 16; ++o) a[o] = t_b2[o0 + o];
        #pragma unroll 8
        for (int cc = 0; cc < 32; ++cc) {   // h1t is LDS (addressable): ok partial
            const unsigned hv = h1t[row48 * 33 + cc];
            const float x0 = bf_lo(hv), x1 = bf_hi(hv);
            #pragma unroll
            for (int ob = 0; ob < 4; ++ob) {
                const float4 w0 = *(const float4*)(t_w2 + (2 * cc) * 64 + o0 + ob * 4);
                const float4 w1 = *(const float4*)(t_w2 + (2 * cc + 1) * 64 + o0 + ob * 4);
                a[ob * 4 + 0] = fmaf(x0, w0.x, a[ob * 4 + 0]);
                a[ob * 4 + 1] = fmaf(x0, w0.y, a[ob * 4 + 1]);
                a[ob * 4 + 2] = fmaf(x0, w0.z, a[ob * 4 + 2]);
                a[ob * 4 + 3] = fmaf(x0, w0.w, a[ob * 4 + 3]);
                a[ob * 4 + 0] = fmaf(x1, w1.x, a[ob * 4 + 0]);
                a[ob * 4 + 1] = fmaf(x1, w1.y, a[ob * 4 + 1]);
                a[ob * 4 + 2] = fmaf(x1, w1.z, a[ob * 4 + 2]);
                a[ob * 4 + 3] = fmaf(x1, w1.w, a[ob * 4 + 3]);
            }
        }
        #pragma unroll
        for (int cc = 0; cc < 8; ++cc)
            h2t[row48 * 33 + q * 8 + cc] =
                pack_bf(fmaxf(a[2 * cc], 0.f), fmaxf(a[2 * cc + 1], 0.f));
    }
    __syncthreads();

    // ===== Phase E3: team layer 3 (64 -> 16, linear) =====
    if (tid < vs * 8) {
        const int s = tid >> 3;
        const int half = (tid >> 2) & 1;
        const int q = tid & 3;
        const int o0 = q * 4;
        const int row48 = s * 2 + half;
        float a0 = t_b3[o0], a1 = t_b3[o0 + 1], a2 = t_b3[o0 + 2], a3 = t_b3[o0 + 3];
        #pragma unroll 8
        for (int cc = 0; cc < 32; ++cc) {   // h2t is LDS: ok partial
            const unsigned hv = h2t[row48 * 33 + cc];
            const float x0 = bf_lo(hv), x1 = bf_hi(hv);
            const float4 w0 = *(const float4*)(t_w3 + (2 * cc) * 16 + o0);
            const float4 w1 = *(const float4*)(t_w3 + (2 * cc + 1) * 16 + o0);
            a0 = fmaf(x0, w0.x, a0); a1 = fmaf(x0, w0.y, a1);
            a2 = fmaf(x0, w0.z, a2); a3 = fmaf(x0, w0.w, a3);
            a0 = fmaf(x1, w1.x, a0); a1 = fmaf(x1, w1.y, a1);
            a2 = fmaf(x1, w1.z, a2); a3 = fmaf(x1, w1.w, a3);
        }
        float* dst = sT + s * 33 + half * 16 + o0;
        dst[0] = a0; dst[1] = a1; dst[2] = a2; dst[3] = a3;
    }
    __syncthreads();

    // ===== Phase F: final MLP (32->16->16->2) + softmax, 1 lane/sample =====
    if (tid < vs) {
        const float* tr = sT + tid * 33;
        float g1[16];
        #pragma unroll
        for (int o = 0; o < 16; ++o) g1[o] = f_b1[o];
        #pragma unroll
        for (int k = 0; k < 32; ++k) {      // tr is LDS, g1 static-indexed
            const float hk = tr[k];
            const float* wr = f_w1 + k * 16;
            #pragma unroll
            for (int o = 0; o < 16; ++o) g1[o] = fmaf(hk, wr[o], g1[o]);
        }
        float g2[16];
        #pragma unroll
        for (int o = 0; o < 16; ++o) g2[o] = f_b2[o];
        #pragma unroll
        for (int k = 0; k < 16; ++k) {      // FULL unroll: g1[k]
            const float hk = fmaxf(g1[k], 0.f);
            const float* wr = f_w2 + k * 16;
            #pragma unroll
            for (int o = 0; o < 16; ++o) g2[o] = fmaf(hk, wr[o], g2[o]);
        }
        float l0 = f_b3[0], l1 = f_b3[1];
        #pragma unroll
        for (int k = 0; k < 16; ++k) {      // FULL unroll: g2[k]
            const float hk = fmaxf(g2[k], 0.f);
            l0 = fmaf(hk, f_w3[2 * k], l0);
            l1 = fmaf(hk, f_w3[2 * k + 1], l1);
        }
        const float e = expf(l1 - l0);
        const float p0 = 1.f / (1.f + e);
        out[(size_t)(s0 + tid) * 2]     = p0;
        out[(size_t)(s0 + tid) * 2 + 1] = 1.f - p0;
    }
}

extern "C" void kernel_launch(void* const* d_in, const int* in_sizes, int n_in,
                              void* d_out, int out_size, void* d_ws, size_t ws_size,
                              hipStream_t stream) {
    (void)in_sizes; (void)n_in; (void)d_ws; (void)ws_size; (void)out_size;
    const float* x    = (const float*)d_in[0];
    const float* h_w1 = (const float*)d_in[1];  const float* h_b1 = (const float*)d_in[2];
    const float* h_w2 = (const float*)d_in[3];  const float* h_b2 = (const float*)d_in[4];
    const float* h_w3 = (const float*)d_in[5];  const float* h_b3 = (const float*)d_in[6];
    const float* c_w1 = (const float*)d_in[7];  const float* c_b1 = (const float*)d_in[8];
    const float* c_w2 = (const float*)d_in[9];  const float* c_b2 = (const float*)d_in[10];
    const float* c_w3 = (const float*)d_in[11]; const float* c_b3 = (const float*)d_in[12];
    const float* t_w1 = (const float*)d_in[13]; const float* t_b1 = (const float*)d_in[14];
    const float* t_w2 = (const float*)d_in[15]; const float* t_b2 = (const float*)d_in[16];
    const float* t_w3 = (const float*)d_in[17]; const float* t_b3 = (const float*)d_in[18];
    const float* f_w1 = (const float*)d_in[19]; const float* f_b1 = (const float*)d_in[20];
    const float* f_w2 = (const float*)d_in[21]; const float* f_b2 = (const float*)d_in[22];
    const float* f_w3 = (const float*)d_in[23]; const float* f_b3 = (const float*)d_in[24];
    float* out = (float*)d_out;

    const int grid = (NB + SPB - 1) / SPB;   // 2622 workgroups
    fused_model_kernel<<<grid, THREADS, 0, stream>>>(
        x, h_w1, h_b1, h_w2, h_b2, h_w3, h_b3,
        c_w1, c_b1, c_w2, c_b2, c_w3, c_b3,
        t_w1, t_b1, t_w2, t_b2, t_w3, t_b3,
        f_w1, f_b1, f_w2, f_b2, f_w3, f_b3,
        out);
}